// Round 16
// baseline (502.051 us; speedup 1.0000x reference)
//
#include <hip/hip_runtime.h>
#include <cstdint>
#include <cstddef>

typedef unsigned short u16;
typedef unsigned int   u32;
typedef __bf16 bf16x8 __attribute__((ext_vector_type(8)));
typedef float  f32x4  __attribute__((ext_vector_type(4)));
static_assert(sizeof(bf16x8) == 16, "bf16x8 must be 16B");
static_assert(sizeof(f32x4) == 16, "f32x4 must be 16B");

#define DEVI static __device__ __forceinline__

// 0.125 (1/sqrt(64)) * log2(e): folded into Q so QK^T lands in exp2-domain.
#define QSCALE 0.18033688011112042f

// bare v_exp_f32 (2^x): inputs here are range-bounded, so skip OCML's wrapper.
DEVI float fexp2(float x) {
  float r;
  asm("v_exp_f32 %0, %1" : "=v"(r) : "v"(x));
  return r;
}

// fp32 -> bf16, round-to-nearest-even
DEVI u16 f2bf(float x) {
  u32 u = __builtin_bit_cast(u32, x);
  u = (u + 0x7FFFu + ((u >> 16) & 1u)) >> 16;
  return (u16)u;
}

// direct HBM -> LDS, 16 bytes per lane. LDS dest must be wave-uniform base;
// HW writes base + lane*16. Global source is per-lane.
DEVI void gload16(const u16* g, u16* l) {
  __builtin_amdgcn_global_load_lds(
      (const __attribute__((address_space(1))) void*)g,
      (__attribute__((address_space(3))) void*)l, 16, 0, 0);
}

#define S_BARRIER() asm volatile("s_barrier" ::: "memory")
#define VMCNT(n) asm volatile("s_waitcnt vmcnt(" #n ")" ::: "memory")

// 16-MFMA cluster: acc[MO..MO+3][0..3] += af x bf   (MO compile-time)
template <int MO, int NACC>
DEVI void mm16(f32x4 (&acc)[NACC][4], const bf16x8 (&af)[4], const bf16x8 (&bf)[4]) {
  __builtin_amdgcn_s_setprio(1);
#pragma unroll
  for (int m = 0; m < 4; m++)
#pragma unroll
    for (int n = 0; n < 4; n++)
      acc[MO + m][n] =
          __builtin_amdgcn_mfma_f32_16x16x32_bf16(af[m], bf[n], acc[MO + m][n], 0, 0, 0);
  __builtin_amdgcn_s_setprio(0);
}

// ---------------------------------------------------------------------------
// Transpose + convert: W[K][N] fp32 -> WT[N][K] bf16; rows n < nscale get *scale
// ---------------------------------------------------------------------------
__global__ __launch_bounds__(256) void transpose_cvt(const float* __restrict__ W,
                                                     u16* __restrict__ WT,
                                                     int K, int N,
                                                     float scale, int nscale) {
  __shared__ float tile[32][33];
  int tx = threadIdx.x & 31, ty = threadIdx.x >> 5;  // 32 x 8
  int c0 = blockIdx.x * 32, r0 = blockIdx.y * 32;
#pragma unroll
  for (int i = 0; i < 4; i++)
    tile[ty + i * 8][tx] = W[(size_t)(r0 + ty + i * 8) * N + c0 + tx];
  __syncthreads();
#pragma unroll
  for (int i = 0; i < 4; i++) {
    int r = ty + i * 8;
    int n = c0 + r;
    float scl = (n < nscale) ? scale : 1.f;
    WT[(size_t)n * K + r0 + tx] = f2bf(tile[tx][r] * scl);
  }
}

// bias prep: biasq[i] = b[i] * (i < 1024 ? QSCALE : 1)   (3072 elems)
__global__ __launch_bounds__(256) void prep_bias(const float* __restrict__ b,
                                                 float* __restrict__ o) {
  int i = blockIdx.x * 256 + threadIdx.x;
  o[i] = b[i] * (i < 1024 ? QSCALE : 1.f);
}

// ---------------------------------------------------------------------------
// LayerNorm: X[row][1024] fp32 -> H[row][1024] bf16   (gamma, beta fp32)
// ---------------------------------------------------------------------------
__global__ __launch_bounds__(256) void ln_k(const float* __restrict__ X,
                                            const float* __restrict__ gam,
                                            const float* __restrict__ bet,
                                            u16* __restrict__ H) {
  __shared__ float2 part[4];
  int row = blockIdx.x, t = threadIdx.x;
  const float4* xr = (const float4*)(X + (size_t)row * 1024);
  float4 v = xr[t];
  float s = v.x + v.y + v.z + v.w;
  float q = v.x * v.x + v.y * v.y + v.z * v.z + v.w * v.w;
#pragma unroll
  for (int o = 32; o > 0; o >>= 1) {
    s += __shfl_xor(s, o);
    q += __shfl_xor(q, o);
  }
  if ((t & 63) == 0) part[t >> 6] = make_float2(s, q);
  __syncthreads();
  float S = part[0].x + part[1].x + part[2].x + part[3].x;
  float Q = part[0].y + part[1].y + part[2].y + part[3].y;
  float mu = S * (1.f / 1024.f);
  float rs = rsqrtf(Q * (1.f / 1024.f) - mu * mu + 1e-5f);
  float4 gv = ((const float4*)gam)[t];
  float4 bv = ((const float4*)bet)[t];
  ushort4 o;
  o.x = f2bf((v.x - mu) * rs * gv.x + bv.x);
  o.y = f2bf((v.y - mu) * rs * gv.y + bv.y);
  o.z = f2bf((v.z - mu) * rs * gv.z + bv.z);
  o.w = f2bf((v.w - mu) * rs * gv.w + bv.w);
  *(ushort4*)(H + (size_t)row * 1024 + t * 4) = o;
}

// ---------------------------------------------------------------------------
// Shared epilogue: wave-tile write-out.
// EPI 2 gelu: sigmoid form (R13-verified, |delta| vs erf ~3e-3).
// ---------------------------------------------------------------------------
template <int EPI, int NACC>
DEVI void epilogue(f32x4 (&acc)[NACC][4], const float* bias, const float* res,
                   float* outF, u16* outB, int N, int rbase, int cbase, int g, int li) {
#pragma unroll
  for (int n = 0; n < 4; n++) {
    int c = cbase + n * 16 + li;
    float bv = bias[c];
#pragma unroll
    for (int a = 0; a < NACC; a++) {
      int rowb = rbase + a * 16 + g * 4;
#pragma unroll
      for (int r = 0; r < 4; r++) {
        size_t idx = (size_t)(rowb + r) * N + c;
        float v = acc[a][n][r] + bv;
        if constexpr (EPI == 1) {
          v += res[idx];
          outF[idx] = v;
        } else if constexpr (EPI == 2) {
          float te = fminf(v * (2.3020246f + 0.10294562f * v * v), 80.f);
          float e = fexp2(te);
          float rc;
          asm("v_rcp_f32 %0, %1" : "=v"(rc) : "v"(e + 1.f));
          v = v * e * rc;
          outB[idx] = f2bf(v);
        } else {
          outB[idx] = f2bf(v);
        }
      }
    }
  }
}

// ---------------------------------------------------------------------------
// gemm256: 256x256 tile, BK=64, 16 waves (1024 thr, 4Mx4N, per-wave 64x64).
// R10 winner -- unchanged. Double-buffered fragment-major LDS (128 KB),
// 2 phases/K-tile, 2 gloads/wave/phase, counted vmcnt(2) ledger.
// ---------------------------------------------------------------------------
template <int EPI>
__global__ __launch_bounds__(1024, 4) void gemm256(const u16* __restrict__ A,
                                                   const u16* __restrict__ Bt,
                                                   const float* __restrict__ bias,
                                                   const float* __restrict__ res,
                                                   float* __restrict__ outF,
                                                   u16* __restrict__ outB,
                                                   int M, int N, int K) {
  __shared__ uint4 As[2][2048];  // 32 frags (kh*16+fm) x 64 lanes, x2 buf
  __shared__ uint4 Bs[2][2048];
  const int t = threadIdx.x, lane = t & 63, wv = t >> 6;  // wv 0..15
  const int wr = wv >> 2, wc = wv & 3;                    // 4M x 4N wave grid
  const int li = lane & 15, g = lane >> 4;

  const int gx = gridDim.x;
  const int nwg = gx * gridDim.y;
  const int wg = blockIdx.y * gx + blockIdx.x;
  const int swz = (wg & 7) * (nwg >> 3) + (wg >> 3);
  const int bx = swz % gx, by = swz / gx;
  const int bm0 = by * 256, bn0 = bx * 256;

  f32x4 acc[4][4];
  const f32x4 z4 = {0.f, 0.f, 0.f, 0.f};
#pragma unroll
  for (int a = 0; a < 4; a++)
#pragma unroll
    for (int n = 0; n < 4; n++) acc[a][n] = z4;

  const u16* aB = A + (size_t)(bm0 + wv * 16 + li) * K + g * 8;
  const u16* bB = Bt + (size_t)(bn0 + wv * 16 + li) * K + g * 8;

  auto stA = [&](int buf, int kh, int kt) {
    gload16(aB + (size_t)kt * 64 + kh * 32, (u16*)&As[buf][(kh * 16 + wv) * 64]);
  };
  auto stB = [&](int buf, int kh, int kt) {
    gload16(bB + (size_t)kt * 64 + kh * 32, (u16*)&Bs[buf][(kh * 16 + wv) * 64]);
  };

  stA(0, 0, 0); stB(0, 0, 0);
  stA(0, 1, 0); stB(0, 1, 0);
  VMCNT(2);
  S_BARRIER();

  const int NT = K >> 6;
  int cur = 0;
  for (int kt = 0; kt < NT; kt++) {
    const int nx = cur ^ 1;
    const bool more = (kt + 1 < NT);
    bf16x8 af[4], bf[4];
    // ---- P0: kh0 ----
#pragma unroll
    for (int n = 0; n < 4; n++)
      bf[n] = __builtin_bit_cast(bf16x8, Bs[cur][(wc * 4 + n) * 64 + lane]);
#pragma unroll
    for (int m = 0; m < 4; m++)
      af[m] = __builtin_bit_cast(bf16x8, As[cur][(wr * 4 + m) * 64 + lane]);
    if (more) { stA(nx, 0, kt + 1); stB(nx, 0, kt + 1); }
    S_BARRIER();
    mm16<0>(acc, af, bf);
    if (more) { VMCNT(2); } else { VMCNT(0); }  // retire cur-kh1
    S_BARRIER();
    // ---- P1: kh1 ----
#pragma unroll
    for (int n = 0; n < 4; n++)
      bf[n] = __builtin_bit_cast(bf16x8, Bs[cur][(16 + wc * 4 + n) * 64 + lane]);
#pragma unroll
    for (int m = 0; m < 4; m++)
      af[m] = __builtin_bit_cast(bf16x8, As[cur][(16 + wr * 4 + m) * 64 + lane]);
    if (more) { stA(nx, 1, kt + 1); stB(nx, 1, kt + 1); }
    S_BARRIER();
    mm16<0>(acc, af, bf);
    if (more) { VMCNT(2); }  // retire nx-kh0 (for next P0)
    S_BARRIER();
    cur = nx;
  }

  epilogue<EPI>(acc, bias, res, outF, outB, N, bm0 + wr * 64, bn0 + wc * 64, g, li);
}

// ---------------------------------------------------------------------------
// gemm128: 128x256 tile, BK=32, 512 thr (8 waves 2Mx4N, per-wave 64x64).
// R14's structure (functionally verified) with the ACTUAL bug fixed:
// launch_bounds(512,2) -> VGPR cap 128 >= 88 needed (R14's (512,6) capped at
// ~85 and spilled acc to scratch: VGPR_Count=40, 1.4 GB writes). 48 KB LDS
// -> 2 blocks/CU = 4 waves/SIMD (2x R15's TLP). Per-wave intensity constant
// (16 MFMA : 8 ds_read, R11 invariant). Tile-granular counted ledger:
// 3 gloads/wave/tile, vmcnt(3) depth-2 in flight.
// ---------------------------------------------------------------------------
template <int EPI>
__global__ __launch_bounds__(512, 2) void gemm128(const u16* __restrict__ A,
                                                  const u16* __restrict__ Bt,
                                                  const float* __restrict__ bias,
                                                  const float* __restrict__ res,
                                                  float* __restrict__ outF,
                                                  u16* __restrict__ outB,
                                                  int M, int N, int K) {
  __shared__ uint4 As[2][512];   // 8 frags x 64 lanes, x2  (16 KB)
  __shared__ uint4 Bs[2][1024];  // 16 frags x 64 lanes, x2 (32 KB)
  const int t = threadIdx.x, lane = t & 63, wv = t >> 6;
  const int wr = wv >> 2, wc = wv & 3;
  const int li = lane & 15, g = lane >> 4;

  const int gx = gridDim.x;
  const int nwg = gx * gridDim.y;
  const int wg = blockIdx.y * gx + blockIdx.x;
  const int swz = (wg & 7) * (nwg >> 3) + (wg >> 3);
  const int bx = swz % gx, by = swz / gx;
  const int bm0 = by * 128, bn0 = bx * 256;

  f32x4 acc[4][4];
  const f32x4 z4 = {0.f, 0.f, 0.f, 0.f};
#pragma unroll
  for (int a = 0; a < 4; a++)
#pragma unroll
    for (int n = 0; n < 4; n++) acc[a][n] = z4;

  // A frag f (0..7): row f*16+li, k = g*8.  B frag f (0..15): col f*16+li.
  const u16* aS = A + (size_t)(bm0 + wv * 16 + li) * K + g * 8;
  const u16* bS0 = Bt + (size_t)(bn0 + wv * 16 + li) * K + g * 8;
  const u16* bS1 = Bt + (size_t)(bn0 + (8 + wv) * 16 + li) * K + g * 8;

  auto stage = [&](int buf, int kt) {
    const size_t ko = (size_t)kt * 32;
    gload16(aS + ko, (u16*)&As[buf][wv * 64]);
    gload16(bS0 + ko, (u16*)&Bs[buf][wv * 64]);
    gload16(bS1 + ko, (u16*)&Bs[buf][(8 + wv) * 64]);
  };

  stage(0, 0);
  stage(1, 1);
  VMCNT(3);  // retire tile0's 3; tile1's 3 in flight
  S_BARRIER();

  const int NT = K >> 5;
  int cur = 0;
  for (int kt = 0; kt < NT; kt++) {
    bf16x8 af[4], bf[4];
#pragma unroll
    for (int n = 0; n < 4; n++)
      bf[n] = __builtin_bit_cast(bf16x8, Bs[cur][(wc * 4 + n) * 64 + lane]);
#pragma unroll
    for (int m = 0; m < 4; m++)
      af[m] = __builtin_bit_cast(bf16x8, As[cur][(wr * 4 + m) * 64 + lane]);
    mm16<0>(acc, af, bf);
    S_BARRIER();  // all waves done reading buf cur
    if (kt + 2 < NT) {
      stage(cur, kt + 2);  // refill cur with tile kt+2
      VMCNT(3);            // retire tile kt+1's 3; kt+2's 3 in flight
      S_BARRIER();
    } else if (kt + 1 < NT) {
      VMCNT(0);
      S_BARRIER();
    }
    cur ^= 1;
  }

  epilogue<EPI>(acc, bias, res, outF, outB, N, bm0 + wr * 64, bn0 + wc * 64, g, li);
}

// ---------------------------------------------------------------------------
// V transpose: qkv V-section -> fragment-major V^T buffer (see R2 notes)
// ---------------------------------------------------------------------------
__global__ __launch_bounds__(256) void v_tr(const u16* __restrict__ qkv,
                                            u16* __restrict__ vfm) {
  __shared__ u16 Vl[64 * 72];
  const int t = threadIdx.x;
  const int bh = blockIdx.y;  // bb*16 + h
  const int bb = bh >> 4, h = bh & 15;
  const int kt = blockIdx.x;  // 0..31
#pragma unroll
  for (int bq = 0; bq < 2; bq++) {
    int c = t + bq * 256;  // 0..511
    int key = c >> 3, d0 = (c & 7) * 8;
    uint4 v = *(const uint4*)(qkv + (size_t)(bb * 2048 + kt * 64 + key) * 3072 + 2048 +
                              h * 64 + d0);
    *(uint4*)&Vl[key * 72 + d0] = v;
  }
  __syncthreads();
#pragma unroll
  for (int bq = 0; bq < 2; bq++) {
    int oc = t + bq * 256;
    int f = oc >> 6, l = oc & 63;
    int db = f >> 1, g32 = f & 1;
    int li = l & 15, g = l >> 4;
    u16 tmp[8];
#pragma unroll
    for (int e = 0; e < 8; e++) {
      int pk = g32 * 32 + ((e & 4) << 2) + g * 4 + (e & 3);
      tmp[e] = Vl[pk * 72 + db * 16 + li];
    }
    *(uint4*)(vfm + ((((size_t)bh * 32 + kt) * 8 + f) * 64 + l) * 8) = *(uint4*)tmp;
  }
}

// ---------------------------------------------------------------------------
// Flash attention, FIXED-BASE softmax, QBLK=128 (R15-validated): each wave
// owns 32 q-rows (two row-groups) -- K/V staging + LDS reads amortized over
// 2x outputs. Unchanged from R15.
// ---------------------------------------------------------------------------
__global__ __launch_bounds__(256) void attn_k(const u16* __restrict__ qkv,
                                              const u16* __restrict__ vfm,
                                              u16* __restrict__ ao) {
  __shared__ uint4 Ks[512];  // 8 frags x 64 x 16B (fragment-major K tile)
  __shared__ uint4 Vs[512];  // 8 frags x 64 x 16B (fragment-major V^T tile)
  const int t = threadIdx.x, lane = t & 63, wv = t >> 6;
  const int g = lane >> 4, li = lane & 15;
  const int bb = blockIdx.y >> 4, h = blockIdx.y & 15;
  const int q0 = blockIdx.x * 128 + wv * 32;

  const size_t qoff0 = (size_t)(bb * 2048 + q0 + li) * 3072 + h * 64 + g * 8;
  const size_t qoff1 = (size_t)(bb * 2048 + q0 + 16 + li) * 3072 + h * 64 + g * 8;
  bf16x8 qf00 = __builtin_bit_cast(bf16x8, *(const uint4*)(qkv + qoff0));
  bf16x8 qf01 = __builtin_bit_cast(bf16x8, *(const uint4*)(qkv + qoff0 + 32));
  bf16x8 qf10 = __builtin_bit_cast(bf16x8, *(const uint4*)(qkv + qoff1));
  bf16x8 qf11 = __builtin_bit_cast(bf16x8, *(const uint4*)(qkv + qoff1 + 32));

  const u16* kbase = qkv + (size_t)bb * 2048 * 3072 + 1024 + h * 64;
  const int f1 = wv + 4;
  const u16* ksrc0 = kbase + (size_t)(((wv >> 1) << 4) + li) * 3072 + ((wv & 1) << 5) + g * 8;
  const u16* ksrc1 = kbase + (size_t)(((f1 >> 1) << 4) + li) * 3072 + ((f1 & 1) << 5) + g * 8;
  const u16* vsrc0 = vfm + ((size_t)(bb * 16 + h) * 32) * 4096 + (wv * 64 + lane) * 8;
  const u16* vsrc1 = vsrc0 + 4 * 64 * 8;

  const f32x4 z4 = {0.f, 0.f, 0.f, 0.f};
  f32x4 Of0[4], Of1[4];
#pragma unroll
  for (int db = 0; db < 4; db++) { Of0[db] = z4; Of1[db] = z4; }
  f32x4 Ol0 = z4, Ol1 = z4;

  bf16x8 vone;
#pragma unroll
  for (int j = 0; j < 8; j++) vone[j] = (__bf16)1.0f;

  for (int tile = 0; tile < 32; tile++) {
    __syncthreads();  // previous tile's LDS reads done
    gload16(ksrc0 + (size_t)tile * 64 * 3072, (u16*)&Ks[wv * 64]);
    gload16(ksrc1 + (size_t)tile * 64 * 3072, (u16*)&Ks[(wv + 4) * 64]);
    gload16(vsrc0 + (size_t)tile * 4096, (u16*)&Vs[wv * 64]);
    gload16(vsrc1 + (size_t)tile * 4096, (u16*)&Vs[(wv + 4) * 64]);
    __syncthreads();  // vmcnt drained: tile ready

#pragma unroll
    for (int g32 = 0; g32 < 2; g32++) {
      uint4 pw0, pw1;
#pragma unroll
      for (int tt = 0; tt < 2; tt++) {
        int kb16 = g32 * 2 + tt;
        bf16x8 k0f = __builtin_bit_cast(bf16x8, Ks[(kb16 * 2 + 0) * 64 + lane]);
        bf16x8 k1f = __builtin_bit_cast(bf16x8, Ks[(kb16 * 2 + 1) * 64 + lane]);
        f32x4 s0 = z4, s1 = z4;
        s0 = __builtin_amdgcn_mfma_f32_16x16x32_bf16(k0f, qf00, s0, 0, 0, 0);
        s0 = __builtin_amdgcn_mfma_f32_16x16x32_bf16(k1f, qf01, s0, 0, 0, 0);
        s1 = __builtin_amdgcn_mfma_f32_16x16x32_bf16(k0f, qf10, s1, 0, 0, 0);
        s1 = __builtin_amdgcn_mfma_f32_16x16x32_bf16(k1f, qf11, s1, 0, 0, 0);
        float a0 = fexp2(s0[0]), a1 = fexp2(s0[1]), a2 = fexp2(s0[2]), a3 = fexp2(s0[3]);
        float b0 = fexp2(s1[0]), b1 = fexp2(s1[1]), b2 = fexp2(s1[2]), b3 = fexp2(s1[3]);
        u32 wa0, wa1, wb0, wb1;
        asm("v_cvt_pk_bf16_f32 %0, %1, %2" : "=v"(wa0) : "v"(a0), "v"(a1));
        asm("v_cvt_pk_bf16_f32 %0, %1, %2" : "=v"(wa1) : "v"(a2), "v"(a3));
        asm("v_cvt_pk_bf16_f32 %0, %1, %2" : "=v"(wb0) : "v"(b0), "v"(b1));
        asm("v_cvt_pk_bf16_f32 %0, %1, %2" : "=v"(wb1) : "v"(b2), "v"(b3));
        if (tt == 0) { pw0.x = wa0; pw0.y = wa1; pw1.x = wb0; pw1.y = wb1; }
        else         { pw0.z = wa0; pw0.w = wa1; pw1.z = wb0; pw1.w = wb1; }
      }
      bf16x8 pfa = __builtin_bit_cast(bf16x8, pw0);
      bf16x8 pfb = __builtin_bit_cast(bf16x8, pw1);
      __builtin_amdgcn_s_setprio(1);
#pragma unroll
      for (int db = 0; db < 4; db++) {
        bf16x8 vf = __builtin_bit_cast(bf16x8, Vs[(db * 2 + g32) * 64 + lane]);
        Of0[db] = __builtin_amdgcn_mfma_f32_16x16x32_bf16(pfa, vf, Of0[db], 0, 0, 0);
        Of1[db] = __builtin_amdgcn_mfma_f32_16x16x32_bf16(pfb, vf, Of1[db], 0, 0, 0);
      }
      Ol0 = __builtin_amdgcn_mfma_f32_16x16x32_bf16(pfa, vone, Ol0, 0, 0, 0);
      Ol1 = __builtin_amdgcn_mfma_f32_16x16x32_bf16(pfb, vone, Ol1, 0, 0, 0);
      __builtin_amdgcn_s_setprio(0);
    }
  }

  float inv0[4], inv1[4];
#pragma unroll
  for (int r = 0; r < 4; r++) { inv0[r] = 1.f / Ol0[r]; inv1[r] = 1.f / Ol1[r]; }
#pragma unroll
  for (int db = 0; db < 4; db++)
#pragma unroll
    for (int r = 0; r < 4; r++) {
      ao[(size_t)(bb * 2048 + q0 + 4 * g + r) * 1024 + h * 64 + db * 16 + li] =
          f2bf(Of0[db][r] * inv0[r]);
      ao[(size_t)(bb * 2048 + q0 + 16 + 4 * g + r) * 1024 + h * 64 + db * 16 + li] =
          f2bf(Of1[db][r] * inv1[r]);
    }
}

// ---------------------------------------------------------------------------
// Launcher
// ---------------------------------------------------------------------------
extern "C" void kernel_launch(void* const* d_in, const int* in_sizes, int n_in,
                              void* d_out, int out_size, void* d_ws, size_t ws_size,
                              hipStream_t stream) {
  const float* x = (const float*)d_in[0];
  const float* ln1g = (const float*)d_in[1];
  const float* ln1b = (const float*)d_in[2];
  const float* wqkv = (const float*)d_in[3];
  const float* bqkv = (const float*)d_in[4];
  const float* wout = (const float*)d_in[5];
  const float* bout = (const float*)d_in[6];
  const float* ln2g = (const float*)d_in[7];
  const float* ln2b = (const float*)d_in[8];
  const float* wff1 = (const float*)d_in[9];
  const float* bff1 = (const float*)d_in[10];
  const float* wff2 = (const float*)d_in[11];
  const float* bff2 = (const float*)d_in[12];
  float* outF = (float*)d_out;
  char* ws = (char*)d_ws;

  u16* wqkvT = (u16*)(ws + 0);         // 3072x1024 bf16 : 6291456 B (Q rows pre-scaled)
  u16* woutT = (u16*)(ws + 6291456);   // 1024x1024 bf16 : 2097152 B
  u16* wff1T = (u16*)(ws + 8388608);   // 4096x1024 bf16 : 8388608 B
  u16* wff2T = (u16*)(ws + 16777216);  // 1024x4096 bf16 : 8388608 B
  u16* hbuf  = (u16*)(ws + 25165824);  // 8192x1024 bf16 : 16777216 B
  u16* vfm   = (u16*)(ws + 25165824);  // 16777216 B; overlays hbuf (dead qkv->ln2)
  u16* qkvb  = (u16*)(ws + 41943040);  // 8192x3072 bf16 : 50331648 B
  u16* attnb = (u16*)(ws + 92274688);  // 8192x1024 bf16 : 16777216 B
  u16* ffn1b = qkvb;                   // 8192x4096 bf16 overlays qkv+attn (dead by then)
  float* biasq = (float*)attnb;        // 12KB scaled qkv bias; consumed by qkv GEMM
                                       // BEFORE attn_k overwrites attnb.

  transpose_cvt<<<dim3(96, 32), 256, 0, stream>>>(wqkv, wqkvT, 1024, 3072, QSCALE, 1024);
  transpose_cvt<<<dim3(32, 32), 256, 0, stream>>>(wout, woutT, 1024, 1024, 1.f, 0);
  transpose_cvt<<<dim3(128, 32), 256, 0, stream>>>(wff1, wff1T, 1024, 4096, 1.f, 0);
  transpose_cvt<<<dim3(32, 128), 256, 0, stream>>>(wff2, wff2T, 4096, 1024, 1.f, 0);
  prep_bias<<<12, 256, 0, stream>>>(bqkv, biasq);

  ln_k<<<8192, 256, 0, stream>>>(x, ln1g, ln1b, hbuf);
  // qkv: 8-wave 128x256 BK=32 (2 blocks/CU), grid 768
  gemm128<0><<<dim3(12, 64), 512, 0, stream>>>(hbuf, wqkvT, biasq, nullptr, nullptr, qkvb,
                                               8192, 3072, 1024);
  v_tr<<<dim3(32, 64), 256, 0, stream>>>(qkvb, vfm);
  // attn: QBLK=128 (4 waves x 32 q-rows), grid 1024
  attn_k<<<dim3(16, 64), 256, 0, stream>>>(qkvb, vfm, attnb);
  gemm128<1><<<dim3(4, 64), 512, 0, stream>>>(attnb, woutT, bout, x, outF, nullptr,
                                              8192, 1024, 1024);
  ln_k<<<8192, 256, 0, stream>>>(outF, ln2g, ln2b, hbuf);
  // ffn1: 16-wave 256^2 kernel, grid 512 = exactly 2 CU-waves
  gemm256<2><<<dim3(16, 32), 1024, 0, stream>>>(hbuf, wff1T, bff1, nullptr, nullptr, ffn1b,
                                                8192, 4096, 1024);
  gemm128<1><<<dim3(4, 64), 512, 0, stream>>>(ffn1b, wff2T, bff2, outF, outF, nullptr,
                                              8192, 1024, 4096);

  (void)in_sizes;
  (void)n_in;
  (void)out_size;
  (void)ws_size;
}

// Round 17
// 434.404 us; speedup vs baseline: 1.1557x; 1.1557x over previous
//
#include <hip/hip_runtime.h>
#include <cstdint>
#include <cstddef>

typedef unsigned short u16;
typedef unsigned int   u32;
typedef __bf16 bf16x8 __attribute__((ext_vector_type(8)));
typedef float  f32x4  __attribute__((ext_vector_type(4)));
static_assert(sizeof(bf16x8) == 16, "bf16x8 must be 16B");
static_assert(sizeof(f32x4) == 16, "f32x4 must be 16B");

#define DEVI static __device__ __forceinline__

// 0.125 (1/sqrt(64)) * log2(e): folded into Q so QK^T lands in exp2-domain.
#define QSCALE 0.18033688011112042f

// bare v_exp_f32 (2^x): inputs here are range-bounded, so skip OCML's wrapper.
DEVI float fexp2(float x) {
  float r;
  asm("v_exp_f32 %0, %1" : "=v"(r) : "v"(x));
  return r;
}

// fp32 -> bf16, round-to-nearest-even
DEVI u16 f2bf(float x) {
  u32 u = __builtin_bit_cast(u32, x);
  u = (u + 0x7FFFu + ((u >> 16) & 1u)) >> 16;
  return (u16)u;
}

// direct HBM -> LDS, 16 bytes per lane. LDS dest must be wave-uniform base;
// HW writes base + lane*16. Global source is per-lane.
DEVI void gload16(const u16* g, u16* l) {
  __builtin_amdgcn_global_load_lds(
      (const __attribute__((address_space(1))) void*)g,
      (__attribute__((address_space(3))) void*)l, 16, 0, 0);
}

#define S_BARRIER() asm volatile("s_barrier" ::: "memory")
#define VMCNT(n) asm volatile("s_waitcnt vmcnt(" #n ")" ::: "memory")

// 16-MFMA cluster: acc[MO..MO+3][0..3] += af x bf   (MO compile-time)
template <int MO, int NACC>
DEVI void mm16(f32x4 (&acc)[NACC][4], const bf16x8 (&af)[4], const bf16x8 (&bf)[4]) {
  __builtin_amdgcn_s_setprio(1);
#pragma unroll
  for (int m = 0; m < 4; m++)
#pragma unroll
    for (int n = 0; n < 4; n++)
      acc[MO + m][n] =
          __builtin_amdgcn_mfma_f32_16x16x32_bf16(af[m], bf[n], acc[MO + m][n], 0, 0, 0);
  __builtin_amdgcn_s_setprio(0);
}

// ---------------------------------------------------------------------------
// Transpose + convert: W[K][N] fp32 -> WT[N][K] bf16; rows n < nscale get *scale
// ---------------------------------------------------------------------------
__global__ __launch_bounds__(256) void transpose_cvt(const float* __restrict__ W,
                                                     u16* __restrict__ WT,
                                                     int K, int N,
                                                     float scale, int nscale) {
  __shared__ float tile[32][33];
  int tx = threadIdx.x & 31, ty = threadIdx.x >> 5;  // 32 x 8
  int c0 = blockIdx.x * 32, r0 = blockIdx.y * 32;
#pragma unroll
  for (int i = 0; i < 4; i++)
    tile[ty + i * 8][tx] = W[(size_t)(r0 + ty + i * 8) * N + c0 + tx];
  __syncthreads();
#pragma unroll
  for (int i = 0; i < 4; i++) {
    int r = ty + i * 8;
    int n = c0 + r;
    float scl = (n < nscale) ? scale : 1.f;
    WT[(size_t)n * K + r0 + tx] = f2bf(tile[tx][r] * scl);
  }
}

// bias prep: biasq[i] = b[i] * (i < 1024 ? QSCALE : 1)   (3072 elems)
__global__ __launch_bounds__(256) void prep_bias(const float* __restrict__ b,
                                                 float* __restrict__ o) {
  int i = blockIdx.x * 256 + threadIdx.x;
  o[i] = b[i] * (i < 1024 ? QSCALE : 1.f);
}

// ---------------------------------------------------------------------------
// LayerNorm: X[row][1024] fp32 -> H[row][1024] bf16   (gamma, beta fp32)
// ---------------------------------------------------------------------------
__global__ __launch_bounds__(256) void ln_k(const float* __restrict__ X,
                                            const float* __restrict__ gam,
                                            const float* __restrict__ bet,
                                            u16* __restrict__ H) {
  __shared__ float2 part[4];
  int row = blockIdx.x, t = threadIdx.x;
  const float4* xr = (const float4*)(X + (size_t)row * 1024);
  float4 v = xr[t];
  float s = v.x + v.y + v.z + v.w;
  float q = v.x * v.x + v.y * v.y + v.z * v.z + v.w * v.w;
#pragma unroll
  for (int o = 32; o > 0; o >>= 1) {
    s += __shfl_xor(s, o);
    q += __shfl_xor(q, o);
  }
  if ((t & 63) == 0) part[t >> 6] = make_float2(s, q);
  __syncthreads();
  float S = part[0].x + part[1].x + part[2].x + part[3].x;
  float Q = part[0].y + part[1].y + part[2].y + part[3].y;
  float mu = S * (1.f / 1024.f);
  float rs = rsqrtf(Q * (1.f / 1024.f) - mu * mu + 1e-5f);
  float4 gv = ((const float4*)gam)[t];
  float4 bv = ((const float4*)bet)[t];
  ushort4 o;
  o.x = f2bf((v.x - mu) * rs * gv.x + bv.x);
  o.y = f2bf((v.y - mu) * rs * gv.y + bv.y);
  o.z = f2bf((v.z - mu) * rs * gv.z + bv.z);
  o.w = f2bf((v.w - mu) * rs * gv.w + bv.w);
  *(ushort4*)(H + (size_t)row * 1024 + t * 4) = o;
}

// ---------------------------------------------------------------------------
// Shared epilogue: wave-tile write-out.
// EPI 2 gelu: sigmoid form (R13-verified, |delta| vs erf ~3e-3).
// ---------------------------------------------------------------------------
template <int EPI, int NACC>
DEVI void epilogue(f32x4 (&acc)[NACC][4], const float* bias, const float* res,
                   float* outF, u16* outB, int N, int rbase, int cbase, int g, int li) {
#pragma unroll
  for (int n = 0; n < 4; n++) {
    int c = cbase + n * 16 + li;
    float bv = bias[c];
#pragma unroll
    for (int a = 0; a < NACC; a++) {
      int rowb = rbase + a * 16 + g * 4;
#pragma unroll
      for (int r = 0; r < 4; r++) {
        size_t idx = (size_t)(rowb + r) * N + c;
        float v = acc[a][n][r] + bv;
        if constexpr (EPI == 1) {
          v += res[idx];
          outF[idx] = v;
        } else if constexpr (EPI == 2) {
          float te = fminf(v * (2.3020246f + 0.10294562f * v * v), 80.f);
          float e = fexp2(te);
          float rc;
          asm("v_rcp_f32 %0, %1" : "=v"(rc) : "v"(e + 1.f));
          v = v * e * rc;
          outB[idx] = f2bf(v);
        } else {
          outB[idx] = f2bf(v);
        }
      }
    }
  }
}

// ---------------------------------------------------------------------------
// gemm256: 256x256 tile, BK=64, 16 waves (1024 thr, 4Mx4N, per-wave 64x64).
// R10 winner -- unchanged. Double-buffered fragment-major LDS (128 KB),
// 2 phases/K-tile, 2 gloads/wave/phase, counted vmcnt(2) ledger.
// ---------------------------------------------------------------------------
template <int EPI>
__global__ __launch_bounds__(1024, 4) void gemm256(const u16* __restrict__ A,
                                                   const u16* __restrict__ Bt,
                                                   const float* __restrict__ bias,
                                                   const float* __restrict__ res,
                                                   float* __restrict__ outF,
                                                   u16* __restrict__ outB,
                                                   int M, int N, int K) {
  __shared__ uint4 As[2][2048];  // 32 frags (kh*16+fm) x 64 lanes, x2 buf
  __shared__ uint4 Bs[2][2048];
  const int t = threadIdx.x, lane = t & 63, wv = t >> 6;  // wv 0..15
  const int wr = wv >> 2, wc = wv & 3;                    // 4M x 4N wave grid
  const int li = lane & 15, g = lane >> 4;

  const int gx = gridDim.x;
  const int nwg = gx * gridDim.y;
  const int wg = blockIdx.y * gx + blockIdx.x;
  const int swz = (wg & 7) * (nwg >> 3) + (wg >> 3);
  const int bx = swz % gx, by = swz / gx;
  const int bm0 = by * 256, bn0 = bx * 256;

  f32x4 acc[4][4];
  const f32x4 z4 = {0.f, 0.f, 0.f, 0.f};
#pragma unroll
  for (int a = 0; a < 4; a++)
#pragma unroll
    for (int n = 0; n < 4; n++) acc[a][n] = z4;

  const u16* aB = A + (size_t)(bm0 + wv * 16 + li) * K + g * 8;
  const u16* bB = Bt + (size_t)(bn0 + wv * 16 + li) * K + g * 8;

  auto stA = [&](int buf, int kh, int kt) {
    gload16(aB + (size_t)kt * 64 + kh * 32, (u16*)&As[buf][(kh * 16 + wv) * 64]);
  };
  auto stB = [&](int buf, int kh, int kt) {
    gload16(bB + (size_t)kt * 64 + kh * 32, (u16*)&Bs[buf][(kh * 16 + wv) * 64]);
  };

  stA(0, 0, 0); stB(0, 0, 0);
  stA(0, 1, 0); stB(0, 1, 0);
  VMCNT(2);
  S_BARRIER();

  const int NT = K >> 6;
  int cur = 0;
  for (int kt = 0; kt < NT; kt++) {
    const int nx = cur ^ 1;
    const bool more = (kt + 1 < NT);
    bf16x8 af[4], bf[4];
    // ---- P0: kh0 ----
#pragma unroll
    for (int n = 0; n < 4; n++)
      bf[n] = __builtin_bit_cast(bf16x8, Bs[cur][(wc * 4 + n) * 64 + lane]);
#pragma unroll
    for (int m = 0; m < 4; m++)
      af[m] = __builtin_bit_cast(bf16x8, As[cur][(wr * 4 + m) * 64 + lane]);
    if (more) { stA(nx, 0, kt + 1); stB(nx, 0, kt + 1); }
    S_BARRIER();
    mm16<0>(acc, af, bf);
    if (more) { VMCNT(2); } else { VMCNT(0); }  // retire cur-kh1
    S_BARRIER();
    // ---- P1: kh1 ----
#pragma unroll
    for (int n = 0; n < 4; n++)
      bf[n] = __builtin_bit_cast(bf16x8, Bs[cur][(16 + wc * 4 + n) * 64 + lane]);
#pragma unroll
    for (int m = 0; m < 4; m++)
      af[m] = __builtin_bit_cast(bf16x8, As[cur][(16 + wr * 4 + m) * 64 + lane]);
    if (more) { stA(nx, 1, kt + 1); stB(nx, 1, kt + 1); }
    S_BARRIER();
    mm16<0>(acc, af, bf);
    if (more) { VMCNT(2); }  // retire nx-kh0 (for next P0)
    S_BARRIER();
    cur = nx;
  }

  epilogue<EPI>(acc, bias, res, outF, outB, N, bm0 + wr * 64, bn0 + wc * 64, g, li);
}

// ---------------------------------------------------------------------------
// gemm128: 128x256 tile, BK=64, 512 thr (8 waves 2Mx4N, per-wave 64x64).
// 2 phases/K-tile, 3 gloads/phase, vmcnt(3) at each phase tail.
// R15-proven version, LOCKED (BK=32 attempts falsified twice: R14 spill,
// R16 regression). 96KB LDS.
// ---------------------------------------------------------------------------
template <int EPI>
__global__ __launch_bounds__(512, 1) void gemm128(const u16* __restrict__ A,
                                                  const u16* __restrict__ Bt,
                                                  const float* __restrict__ bias,
                                                  const float* __restrict__ res,
                                                  float* __restrict__ outF,
                                                  u16* __restrict__ outB,
                                                  int M, int N, int K) {
  __shared__ uint4 As[2][1024];
  __shared__ uint4 Bs[2][2048];
  const int t = threadIdx.x, lane = t & 63, wv = t >> 6;
  const int wr = wv >> 2, wc = wv & 3;
  const int li = lane & 15, g = lane >> 4;

  const int gx = gridDim.x;
  const int nwg = gx * gridDim.y;
  const int wg = blockIdx.y * gx + blockIdx.x;
  const int swz = (wg & 7) * (nwg >> 3) + (wg >> 3);
  const int bx = swz % gx, by = swz / gx;
  const int bm0 = by * 128, bn0 = bx * 256;

  f32x4 acc[4][4];
  const f32x4 z4 = {0.f, 0.f, 0.f, 0.f};
#pragma unroll
  for (int a = 0; a < 4; a++)
#pragma unroll
    for (int n = 0; n < 4; n++) acc[a][n] = z4;

  const u16* aB = A + (size_t)(bm0 + wv * 16 + li) * K + g * 8;
  const u16* bB = Bt + (size_t)(bn0 + wv * 16 + li) * K + g * 8;
  const size_t rskip = (size_t)128 * K;

  auto stA = [&](int buf, int j, int kt) {
    gload16(aB + (size_t)kt * 64 + j * 32, (u16*)&As[buf][(j * 8 + wv) * 64]);
  };
  auto stB = [&](int buf, int j, int kt) {
    gload16(bB + (size_t)kt * 64 + ((j & 1) ? rskip : (size_t)0) + (j >> 1) * 32,
            (u16*)&Bs[buf][(j * 8 + wv) * 64]);
  };

  stA(0, 0, 0); stB(0, 0, 0); stB(0, 1, 0);
  stA(0, 1, 0); stB(0, 2, 0); stB(0, 3, 0);
  VMCNT(3);
  S_BARRIER();

  const int NT = K >> 6;
  int cur = 0;
  for (int kt = 0; kt < NT; kt++) {
    const int nx = cur ^ 1;
    const bool more = (kt + 1 < NT);
    bf16x8 af[4], bf[4];
#pragma unroll
    for (int n = 0; n < 4; n++)
      bf[n] = __builtin_bit_cast(bf16x8, Bs[cur][(wc * 4 + n) * 64 + lane]);
#pragma unroll
    for (int m = 0; m < 4; m++)
      af[m] = __builtin_bit_cast(bf16x8, As[cur][(wr * 4 + m) * 64 + lane]);
    if (more) { stA(nx, 0, kt + 1); stB(nx, 0, kt + 1); stB(nx, 1, kt + 1); }
    S_BARRIER();
    mm16<0>(acc, af, bf);
    if (more) { VMCNT(3); } else { VMCNT(0); }
    S_BARRIER();
#pragma unroll
    for (int n = 0; n < 4; n++)
      bf[n] = __builtin_bit_cast(bf16x8, Bs[cur][(16 + wc * 4 + n) * 64 + lane]);
#pragma unroll
    for (int m = 0; m < 4; m++)
      af[m] = __builtin_bit_cast(bf16x8, As[cur][(8 + wr * 4 + m) * 64 + lane]);
    if (more) { stA(nx, 1, kt + 1); stB(nx, 2, kt + 1); stB(nx, 3, kt + 1); }
    S_BARRIER();
    mm16<0>(acc, af, bf);
    if (more) { VMCNT(3); }
    S_BARRIER();
    cur = nx;
  }

  epilogue<EPI>(acc, bias, res, outF, outB, N, bm0 + wr * 64, bn0 + wc * 64, g, li);
}

// ---------------------------------------------------------------------------
// V transpose: qkv V-section -> fragment-major V^T buffer (see R2 notes)
// ---------------------------------------------------------------------------
__global__ __launch_bounds__(256) void v_tr(const u16* __restrict__ qkv,
                                            u16* __restrict__ vfm) {
  __shared__ u16 Vl[64 * 72];
  const int t = threadIdx.x;
  const int bh = blockIdx.y;  // bb*16 + h
  const int bb = bh >> 4, h = bh & 15;
  const int kt = blockIdx.x;  // 0..31
#pragma unroll
  for (int bq = 0; bq < 2; bq++) {
    int c = t + bq * 256;  // 0..511
    int key = c >> 3, d0 = (c & 7) * 8;
    uint4 v = *(const uint4*)(qkv + (size_t)(bb * 2048 + kt * 64 + key) * 3072 + 2048 +
                              h * 64 + d0);
    *(uint4*)&Vl[key * 72 + d0] = v;
  }
  __syncthreads();
#pragma unroll
  for (int bq = 0; bq < 2; bq++) {
    int oc = t + bq * 256;
    int f = oc >> 6, l = oc & 63;
    int db = f >> 1, g32 = f & 1;
    int li = l & 15, g = l >> 4;
    u16 tmp[8];
#pragma unroll
    for (int e = 0; e < 8; e++) {
      int pk = g32 * 32 + ((e & 4) << 2) + g * 4 + (e & 3);
      tmp[e] = Vl[pk * 72 + db * 16 + li];
    }
    *(uint4*)(vfm + ((((size_t)bh * 32 + kt) * 8 + f) * 64 + l) * 8) = *(uint4*)tmp;
  }
}

// ---------------------------------------------------------------------------
// Flash attention, FIXED-BASE softmax, QBLK=128 x KVBLK=128.
// Composition of two verified pieces: R6's 16-fragment K/V staging + P->V
// mapping for 128-key tiles (passed), and R15's two-row-group QBLK=128
// compute (passed). Single-buffered (R7 dbuf regression not repeated).
// 32 KB LDS; per 128 keys: 2 barriers (was 4), 8 gloads (same), fixed costs
// halved. 72 MFMA + 64 exp + 32 cvt_pk per tile per wave.
// ---------------------------------------------------------------------------
__global__ __launch_bounds__(256) void attn_k(const u16* __restrict__ qkv,
                                              const u16* __restrict__ vfm,
                                              u16* __restrict__ ao) {
  __shared__ uint4 Ks[1024];  // 16 frags x 64 x 16B (128 keys x 64 d)
  __shared__ uint4 Vs[1024];  // 16 frags x 64 x 16B (two 64-key vfm blocks)
  const int t = threadIdx.x, lane = t & 63, wv = t >> 6;
  const int g = lane >> 4, li = lane & 15;
  const int bb = blockIdx.y >> 4, h = blockIdx.y & 15;
  const int q0 = blockIdx.x * 128 + wv * 32;

  const size_t qoff0 = (size_t)(bb * 2048 + q0 + li) * 3072 + h * 64 + g * 8;
  const size_t qoff1 = (size_t)(bb * 2048 + q0 + 16 + li) * 3072 + h * 64 + g * 8;
  bf16x8 qf00 = __builtin_bit_cast(bf16x8, *(const uint4*)(qkv + qoff0));
  bf16x8 qf01 = __builtin_bit_cast(bf16x8, *(const uint4*)(qkv + qoff0 + 32));
  bf16x8 qf10 = __builtin_bit_cast(bf16x8, *(const uint4*)(qkv + qoff1));
  bf16x8 qf11 = __builtin_bit_cast(bf16x8, *(const uint4*)(qkv + qoff1 + 32));

  // K frag f (0..15): key_in_tile = (f>>1)*16 + li, d = (f&1)*32 + g*8.
  // V frag f (0..15): kt64 block f>>3, within-block frag f&7 (R6-verified).
  // Wave wv stages f in {wv, wv+4, wv+8, wv+12}.
  const u16* kbase = qkv + (size_t)bb * 2048 * 3072 + 1024 + h * 64;
  const u16* vbase = vfm + (size_t)(bb * 16 + h) * 32 * 4096;
  const u16* ksrc[4];
  const u16* vsrc[4];
#pragma unroll
  for (int j = 0; j < 4; j++) {
    int f = wv + j * 4;
    ksrc[j] = kbase + (size_t)(((f >> 1) << 4) + li) * 3072 + ((f & 1) << 5) + g * 8;
    vsrc[j] = vbase + (size_t)(f >> 3) * 4096 + ((f & 7) * 64 + lane) * 8;
  }

  const f32x4 z4 = {0.f, 0.f, 0.f, 0.f};
  f32x4 Of0[4], Of1[4];
#pragma unroll
  for (int db = 0; db < 4; db++) { Of0[db] = z4; Of1[db] = z4; }
  f32x4 Ol0 = z4, Ol1 = z4;

  bf16x8 vone;
#pragma unroll
  for (int j = 0; j < 8; j++) vone[j] = (__bf16)1.0f;

  for (int tile = 0; tile < 16; tile++) {
    __syncthreads();  // previous tile's LDS reads done
#pragma unroll
    for (int j = 0; j < 4; j++) {
      int f = wv + j * 4;
      gload16(ksrc[j] + (size_t)tile * 128 * 3072, (u16*)&Ks[f * 64]);
      gload16(vsrc[j] + (size_t)tile * 8192, (u16*)&Vs[f * 64]);
    }
    __syncthreads();  // vmcnt drained: tile ready

#pragma unroll
    for (int g32 = 0; g32 < 4; g32++) {
      uint4 pw0, pw1;
#pragma unroll
      for (int tt = 0; tt < 2; tt++) {
        int kb16 = g32 * 2 + tt;
        bf16x8 k0f = __builtin_bit_cast(bf16x8, Ks[(kb16 * 2 + 0) * 64 + lane]);
        bf16x8 k1f = __builtin_bit_cast(bf16x8, Ks[(kb16 * 2 + 1) * 64 + lane]);
        f32x4 s0 = z4, s1 = z4;
        s0 = __builtin_amdgcn_mfma_f32_16x16x32_bf16(k0f, qf00, s0, 0, 0, 0);
        s0 = __builtin_amdgcn_mfma_f32_16x16x32_bf16(k1f, qf01, s0, 0, 0, 0);
        s1 = __builtin_amdgcn_mfma_f32_16x16x32_bf16(k0f, qf10, s1, 0, 0, 0);
        s1 = __builtin_amdgcn_mfma_f32_16x16x32_bf16(k1f, qf11, s1, 0, 0, 0);
        float a0 = fexp2(s0[0]), a1 = fexp2(s0[1]), a2 = fexp2(s0[2]), a3 = fexp2(s0[3]);
        float b0 = fexp2(s1[0]), b1 = fexp2(s1[1]), b2 = fexp2(s1[2]), b3 = fexp2(s1[3]);
        u32 wa0, wa1, wb0, wb1;
        asm("v_cvt_pk_bf16_f32 %0, %1, %2" : "=v"(wa0) : "v"(a0), "v"(a1));
        asm("v_cvt_pk_bf16_f32 %0, %1, %2" : "=v"(wa1) : "v"(a2), "v"(a3));
        asm("v_cvt_pk_bf16_f32 %0, %1, %2" : "=v"(wb0) : "v"(b0), "v"(b1));
        asm("v_cvt_pk_bf16_f32 %0, %1, %2" : "=v"(wb1) : "v"(b2), "v"(b3));
        if (tt == 0) { pw0.x = wa0; pw0.y = wa1; pw1.x = wb0; pw1.y = wb1; }
        else         { pw0.z = wa0; pw0.w = wa1; pw1.z = wb0; pw1.w = wb1; }
      }
      bf16x8 pfa = __builtin_bit_cast(bf16x8, pw0);
      bf16x8 pfb = __builtin_bit_cast(bf16x8, pw1);
      const int fb = (g32 >> 1) * 8 + (g32 & 1);  // + db*2 below (R6-verified)
      __builtin_amdgcn_s_setprio(1);
#pragma unroll
      for (int db = 0; db < 4; db++) {
        bf16x8 vf = __builtin_bit_cast(bf16x8, Vs[(fb + db * 2) * 64 + lane]);
        Of0[db] = __builtin_amdgcn_mfma_f32_16x16x32_bf16(pfa, vf, Of0[db], 0, 0, 0);
        Of1[db] = __builtin_amdgcn_mfma_f32_16x16x32_bf16(pfb, vf, Of1[db], 0, 0, 0);
      }
      Ol0 = __builtin_amdgcn_mfma_f32_16x16x32_bf16(pfa, vone, Ol0, 0, 0, 0);
      Ol1 = __builtin_amdgcn_mfma_f32_16x16x32_bf16(pfb, vone, Ol1, 0, 0, 0);
      __builtin_amdgcn_s_setprio(0);
    }
  }

  float inv0[4], inv1[4];
#pragma unroll
  for (int r = 0; r < 4; r++) { inv0[r] = 1.f / Ol0[r]; inv1[r] = 1.f / Ol1[r]; }
#pragma unroll
  for (int db = 0; db < 4; db++)
#pragma unroll
    for (int r = 0; r < 4; r++) {
      ao[(size_t)(bb * 2048 + q0 + 4 * g + r) * 1024 + h * 64 + db * 16 + li] =
          f2bf(Of0[db][r] * inv0[r]);
      ao[(size_t)(bb * 2048 + q0 + 16 + 4 * g + r) * 1024 + h * 64 + db * 16 + li] =
          f2bf(Of1[db][r] * inv1[r]);
    }
}

// ---------------------------------------------------------------------------
// Launcher
// ---------------------------------------------------------------------------
extern "C" void kernel_launch(void* const* d_in, const int* in_sizes, int n_in,
                              void* d_out, int out_size, void* d_ws, size_t ws_size,
                              hipStream_t stream) {
  const float* x = (const float*)d_in[0];
  const float* ln1g = (const float*)d_in[1];
  const float* ln1b = (const float*)d_in[2];
  const float* wqkv = (const float*)d_in[3];
  const float* bqkv = (const float*)d_in[4];
  const float* wout = (const float*)d_in[5];
  const float* bout = (const float*)d_in[6];
  const float* ln2g = (const float*)d_in[7];
  const float* ln2b = (const float*)d_in[8];
  const float* wff1 = (const float*)d_in[9];
  const float* bff1 = (const float*)d_in[10];
  const float* wff2 = (const float*)d_in[11];
  const float* bff2 = (const float*)d_in[12];
  float* outF = (float*)d_out;
  char* ws = (char*)d_ws;

  u16* wqkvT = (u16*)(ws + 0);         // 3072x1024 bf16 : 6291456 B (Q rows pre-scaled)
  u16* woutT = (u16*)(ws + 6291456);   // 1024x1024 bf16 : 2097152 B
  u16* wff1T = (u16*)(ws + 8388608);   // 4096x1024 bf16 : 8388608 B
  u16* wff2T = (u16*)(ws + 16777216);  // 1024x4096 bf16 : 8388608 B
  u16* hbuf  = (u16*)(ws + 25165824);  // 8192x1024 bf16 : 16777216 B
  u16* vfm   = (u16*)(ws + 25165824);  // 16777216 B; overlays hbuf (dead qkv->ln2)
  u16* qkvb  = (u16*)(ws + 41943040);  // 8192x3072 bf16 : 50331648 B
  u16* attnb = (u16*)(ws + 92274688);  // 8192x1024 bf16 : 16777216 B
  u16* ffn1b = qkvb;                   // 8192x4096 bf16 overlays qkv+attn (dead by then)
  float* biasq = (float*)attnb;        // 12KB scaled qkv bias; consumed by qkv GEMM
                                       // BEFORE attn_k overwrites attnb.

  transpose_cvt<<<dim3(96, 32), 256, 0, stream>>>(wqkv, wqkvT, 1024, 3072, QSCALE, 1024);
  transpose_cvt<<<dim3(32, 32), 256, 0, stream>>>(wout, woutT, 1024, 1024, 1.f, 0);
  transpose_cvt<<<dim3(128, 32), 256, 0, stream>>>(wff1, wff1T, 1024, 4096, 1.f, 0);
  transpose_cvt<<<dim3(32, 128), 256, 0, stream>>>(wff2, wff2T, 4096, 1024, 1.f, 0);
  prep_bias<<<12, 256, 0, stream>>>(bqkv, biasq);

  ln_k<<<8192, 256, 0, stream>>>(x, ln1g, ln1b, hbuf);
  // qkv: 8-wave 128x256 BK=64 (R15 config), grid 768 = 3 exact CU-waves
  gemm128<0><<<dim3(12, 64), 512, 0, stream>>>(hbuf, wqkvT, biasq, nullptr, nullptr, qkvb,
                                               8192, 3072, 1024);
  v_tr<<<dim3(32, 64), 256, 0, stream>>>(qkvb, vfm);
  // attn: QBLK=128 x KVBLK=128, grid 1024
  attn_k<<<dim3(16, 64), 256, 0, stream>>>(qkvb, vfm, attnb);
  gemm128<1><<<dim3(4, 64), 512, 0, stream>>>(attnb, woutT, bout, x, outF, nullptr,
                                              8192, 1024, 1024);
  ln_k<<<8192, 256, 0, stream>>>(outF, ln2g, ln2b, hbuf);
  // ffn1: 16-wave 256^2 kernel, grid 512 = exactly 2 CU-waves
  gemm256<2><<<dim3(16, 32), 1024, 0, stream>>>(hbuf, wff1T, bff1, nullptr, nullptr, ffn1b,
                                                8192, 4096, 1024);
  gemm128<1><<<dim3(4, 64), 512, 0, stream>>>(ffn1b, wff2T, bff2, outF, outF, nullptr,
                                              8192, 1024, 4096);

  (void)in_sizes;
  (void)n_in;
  (void)out_size;
  (void)ws_size;
}

// Round 18
// 430.060 us; speedup vs baseline: 1.1674x; 1.0101x over previous
//
#include <hip/hip_runtime.h>
#include <cstdint>
#include <cstddef>

typedef unsigned short u16;
typedef unsigned int   u32;
typedef __bf16 bf16x8 __attribute__((ext_vector_type(8)));
typedef float  f32x4  __attribute__((ext_vector_type(4)));
static_assert(sizeof(bf16x8) == 16, "bf16x8 must be 16B");
static_assert(sizeof(f32x4) == 16, "f32x4 must be 16B");

#define DEVI static __device__ __forceinline__

// 0.125 (1/sqrt(64)) * log2(e): folded into Q so QK^T lands in exp2-domain.
#define QSCALE 0.18033688011112042f

// bare v_exp_f32 (2^x): inputs here are range-bounded, so skip OCML's wrapper.
DEVI float fexp2(float x) {
  float r;
  asm("v_exp_f32 %0, %1" : "=v"(r) : "v"(x));
  return r;
}

// fp32 -> bf16, round-to-nearest-even
DEVI u16 f2bf(float x) {
  u32 u = __builtin_bit_cast(u32, x);
  u = (u + 0x7FFFu + ((u >> 16) & 1u)) >> 16;
  return (u16)u;
}

// direct HBM -> LDS, 16 bytes per lane. LDS dest must be wave-uniform base;
// HW writes base + lane*16. Global source is per-lane.
DEVI void gload16(const u16* g, u16* l) {
  __builtin_amdgcn_global_load_lds(
      (const __attribute__((address_space(1))) void*)g,
      (__attribute__((address_space(3))) void*)l, 16, 0, 0);
}

#define S_BARRIER() asm volatile("s_barrier" ::: "memory")
#define VMCNT(n) asm volatile("s_waitcnt vmcnt(" #n ")" ::: "memory")

// 16-MFMA cluster: acc[MO..MO+3][0..3] += af x bf   (MO compile-time)
template <int MO, int NACC>
DEVI void mm16(f32x4 (&acc)[NACC][4], const bf16x8 (&af)[4], const bf16x8 (&bf)[4]) {
  __builtin_amdgcn_s_setprio(1);
#pragma unroll
  for (int m = 0; m < 4; m++)
#pragma unroll
    for (int n = 0; n < 4; n++)
      acc[MO + m][n] =
          __builtin_amdgcn_mfma_f32_16x16x32_bf16(af[m], bf[n], acc[MO + m][n], 0, 0, 0);
  __builtin_amdgcn_s_setprio(0);
}

// ---------------------------------------------------------------------------
// Transpose + convert: W[K][N] fp32 -> WT[N][K] bf16; rows n < nscale get *scale
// ---------------------------------------------------------------------------
__global__ __launch_bounds__(256) void transpose_cvt(const float* __restrict__ W,
                                                     u16* __restrict__ WT,
                                                     int K, int N,
                                                     float scale, int nscale) {
  __shared__ float tile[32][33];
  int tx = threadIdx.x & 31, ty = threadIdx.x >> 5;  // 32 x 8
  int c0 = blockIdx.x * 32, r0 = blockIdx.y * 32;
#pragma unroll
  for (int i = 0; i < 4; i++)
    tile[ty + i * 8][tx] = W[(size_t)(r0 + ty + i * 8) * N + c0 + tx];
  __syncthreads();
#pragma unroll
  for (int i = 0; i < 4; i++) {
    int r = ty + i * 8;
    int n = c0 + r;
    float scl = (n < nscale) ? scale : 1.f;
    WT[(size_t)n * K + r0 + tx] = f2bf(tile[tx][r] * scl);
  }
}

// bias prep: biasq[i] = b[i] * (i < 1024 ? QSCALE : 1)   (3072 elems)
__global__ __launch_bounds__(256) void prep_bias(const float* __restrict__ b,
                                                 float* __restrict__ o) {
  int i = blockIdx.x * 256 + threadIdx.x;
  o[i] = b[i] * (i < 1024 ? QSCALE : 1.f);
}

// ---------------------------------------------------------------------------
// LayerNorm: X[row][1024] fp32 -> H[row][1024] bf16   (gamma, beta fp32)
// ---------------------------------------------------------------------------
__global__ __launch_bounds__(256) void ln_k(const float* __restrict__ X,
                                            const float* __restrict__ gam,
                                            const float* __restrict__ bet,
                                            u16* __restrict__ H) {
  __shared__ float2 part[4];
  int row = blockIdx.x, t = threadIdx.x;
  const float4* xr = (const float4*)(X + (size_t)row * 1024);
  float4 v = xr[t];
  float s = v.x + v.y + v.z + v.w;
  float q = v.x * v.x + v.y * v.y + v.z * v.z + v.w * v.w;
#pragma unroll
  for (int o = 32; o > 0; o >>= 1) {
    s += __shfl_xor(s, o);
    q += __shfl_xor(q, o);
  }
  if ((t & 63) == 0) part[t >> 6] = make_float2(s, q);
  __syncthreads();
  float S = part[0].x + part[1].x + part[2].x + part[3].x;
  float Q = part[0].y + part[1].y + part[2].y + part[3].y;
  float mu = S * (1.f / 1024.f);
  float rs = rsqrtf(Q * (1.f / 1024.f) - mu * mu + 1e-5f);
  float4 gv = ((const float4*)gam)[t];
  float4 bv = ((const float4*)bet)[t];
  ushort4 o;
  o.x = f2bf((v.x - mu) * rs * gv.x + bv.x);
  o.y = f2bf((v.y - mu) * rs * gv.y + bv.y);
  o.z = f2bf((v.z - mu) * rs * gv.z + bv.z);
  o.w = f2bf((v.w - mu) * rs * gv.w + bv.w);
  *(ushort4*)(H + (size_t)row * 1024 + t * 4) = o;
}

// ---------------------------------------------------------------------------
// Shared epilogue: wave-tile write-out.
// EPI 2 gelu: sigmoid form (R13-verified, |delta| vs erf ~3e-3).
// ---------------------------------------------------------------------------
template <int EPI, int NACC>
DEVI void epilogue(f32x4 (&acc)[NACC][4], const float* bias, const float* res,
                   float* outF, u16* outB, int N, int rbase, int cbase, int g, int li) {
#pragma unroll
  for (int n = 0; n < 4; n++) {
    int c = cbase + n * 16 + li;
    float bv = bias[c];
#pragma unroll
    for (int a = 0; a < NACC; a++) {
      int rowb = rbase + a * 16 + g * 4;
#pragma unroll
      for (int r = 0; r < 4; r++) {
        size_t idx = (size_t)(rowb + r) * N + c;
        float v = acc[a][n][r] + bv;
        if constexpr (EPI == 1) {
          v += res[idx];
          outF[idx] = v;
        } else if constexpr (EPI == 2) {
          float te = fminf(v * (2.3020246f + 0.10294562f * v * v), 80.f);
          float e = fexp2(te);
          float rc;
          asm("v_rcp_f32 %0, %1" : "=v"(rc) : "v"(e + 1.f));
          v = v * e * rc;
          outB[idx] = f2bf(v);
        } else {
          outB[idx] = f2bf(v);
        }
      }
    }
  }
}

// ---------------------------------------------------------------------------
// gemm256: 256x256 tile, BK=64, 16 waves (1024 thr, 4Mx4N, per-wave 64x64).
// R10 winner -- unchanged. Double-buffered fragment-major LDS (128 KB),
// 2 phases/K-tile, 2 gloads/wave/phase, counted vmcnt(2) ledger.
// ---------------------------------------------------------------------------
template <int EPI>
__global__ __launch_bounds__(1024, 4) void gemm256(const u16* __restrict__ A,
                                                   const u16* __restrict__ Bt,
                                                   const float* __restrict__ bias,
                                                   const float* __restrict__ res,
                                                   float* __restrict__ outF,
                                                   u16* __restrict__ outB,
                                                   int M, int N, int K) {
  __shared__ uint4 As[2][2048];  // 32 frags (kh*16+fm) x 64 lanes, x2 buf
  __shared__ uint4 Bs[2][2048];
  const int t = threadIdx.x, lane = t & 63, wv = t >> 6;  // wv 0..15
  const int wr = wv >> 2, wc = wv & 3;                    // 4M x 4N wave grid
  const int li = lane & 15, g = lane >> 4;

  const int gx = gridDim.x;
  const int nwg = gx * gridDim.y;
  const int wg = blockIdx.y * gx + blockIdx.x;
  const int swz = (wg & 7) * (nwg >> 3) + (wg >> 3);
  const int bx = swz % gx, by = swz / gx;
  const int bm0 = by * 256, bn0 = bx * 256;

  f32x4 acc[4][4];
  const f32x4 z4 = {0.f, 0.f, 0.f, 0.f};
#pragma unroll
  for (int a = 0; a < 4; a++)
#pragma unroll
    for (int n = 0; n < 4; n++) acc[a][n] = z4;

  const u16* aB = A + (size_t)(bm0 + wv * 16 + li) * K + g * 8;
  const u16* bB = Bt + (size_t)(bn0 + wv * 16 + li) * K + g * 8;

  auto stA = [&](int buf, int kh, int kt) {
    gload16(aB + (size_t)kt * 64 + kh * 32, (u16*)&As[buf][(kh * 16 + wv) * 64]);
  };
  auto stB = [&](int buf, int kh, int kt) {
    gload16(bB + (size_t)kt * 64 + kh * 32, (u16*)&Bs[buf][(kh * 16 + wv) * 64]);
  };

  stA(0, 0, 0); stB(0, 0, 0);
  stA(0, 1, 0); stB(0, 1, 0);
  VMCNT(2);
  S_BARRIER();

  const int NT = K >> 6;
  int cur = 0;
  for (int kt = 0; kt < NT; kt++) {
    const int nx = cur ^ 1;
    const bool more = (kt + 1 < NT);
    bf16x8 af[4], bf[4];
    // ---- P0: kh0 ----
#pragma unroll
    for (int n = 0; n < 4; n++)
      bf[n] = __builtin_bit_cast(bf16x8, Bs[cur][(wc * 4 + n) * 64 + lane]);
#pragma unroll
    for (int m = 0; m < 4; m++)
      af[m] = __builtin_bit_cast(bf16x8, As[cur][(wr * 4 + m) * 64 + lane]);
    if (more) { stA(nx, 0, kt + 1); stB(nx, 0, kt + 1); }
    S_BARRIER();
    mm16<0>(acc, af, bf);
    if (more) { VMCNT(2); } else { VMCNT(0); }  // retire cur-kh1
    S_BARRIER();
    // ---- P1: kh1 ----
#pragma unroll
    for (int n = 0; n < 4; n++)
      bf[n] = __builtin_bit_cast(bf16x8, Bs[cur][(16 + wc * 4 + n) * 64 + lane]);
#pragma unroll
    for (int m = 0; m < 4; m++)
      af[m] = __builtin_bit_cast(bf16x8, As[cur][(16 + wr * 4 + m) * 64 + lane]);
    if (more) { stA(nx, 1, kt + 1); stB(nx, 1, kt + 1); }
    S_BARRIER();
    mm16<0>(acc, af, bf);
    if (more) { VMCNT(2); }  // retire nx-kh0 (for next P0)
    S_BARRIER();
    cur = nx;
  }

  epilogue<EPI>(acc, bias, res, outF, outB, N, bm0 + wr * 64, bn0 + wc * 64, g, li);
}

// ---------------------------------------------------------------------------
// gemm128: 128x256 tile, BK=64, 512 thr (8 waves 2Mx4N, per-wave 64x64).
// 2 phases/K-tile, 3 gloads/phase, vmcnt(3) at each phase tail.
// R15-proven version, LOCKED (BK=32 attempts falsified twice). 96KB LDS.
// ---------------------------------------------------------------------------
template <int EPI>
__global__ __launch_bounds__(512, 1) void gemm128(const u16* __restrict__ A,
                                                  const u16* __restrict__ Bt,
                                                  const float* __restrict__ bias,
                                                  const float* __restrict__ res,
                                                  float* __restrict__ outF,
                                                  u16* __restrict__ outB,
                                                  int M, int N, int K) {
  __shared__ uint4 As[2][1024];
  __shared__ uint4 Bs[2][2048];
  const int t = threadIdx.x, lane = t & 63, wv = t >> 6;
  const int wr = wv >> 2, wc = wv & 3;
  const int li = lane & 15, g = lane >> 4;

  const int gx = gridDim.x;
  const int nwg = gx * gridDim.y;
  const int wg = blockIdx.y * gx + blockIdx.x;
  const int swz = (wg & 7) * (nwg >> 3) + (wg >> 3);
  const int bx = swz % gx, by = swz / gx;
  const int bm0 = by * 128, bn0 = bx * 256;

  f32x4 acc[4][4];
  const f32x4 z4 = {0.f, 0.f, 0.f, 0.f};
#pragma unroll
  for (int a = 0; a < 4; a++)
#pragma unroll
    for (int n = 0; n < 4; n++) acc[a][n] = z4;

  const u16* aB = A + (size_t)(bm0 + wv * 16 + li) * K + g * 8;
  const u16* bB = Bt + (size_t)(bn0 + wv * 16 + li) * K + g * 8;
  const size_t rskip = (size_t)128 * K;

  auto stA = [&](int buf, int j, int kt) {
    gload16(aB + (size_t)kt * 64 + j * 32, (u16*)&As[buf][(j * 8 + wv) * 64]);
  };
  auto stB = [&](int buf, int j, int kt) {
    gload16(bB + (size_t)kt * 64 + ((j & 1) ? rskip : (size_t)0) + (j >> 1) * 32,
            (u16*)&Bs[buf][(j * 8 + wv) * 64]);
  };

  stA(0, 0, 0); stB(0, 0, 0); stB(0, 1, 0);
  stA(0, 1, 0); stB(0, 2, 0); stB(0, 3, 0);
  VMCNT(3);
  S_BARRIER();

  const int NT = K >> 6;
  int cur = 0;
  for (int kt = 0; kt < NT; kt++) {
    const int nx = cur ^ 1;
    const bool more = (kt + 1 < NT);
    bf16x8 af[4], bf[4];
#pragma unroll
    for (int n = 0; n < 4; n++)
      bf[n] = __builtin_bit_cast(bf16x8, Bs[cur][(wc * 4 + n) * 64 + lane]);
#pragma unroll
    for (int m = 0; m < 4; m++)
      af[m] = __builtin_bit_cast(bf16x8, As[cur][(wr * 4 + m) * 64 + lane]);
    if (more) { stA(nx, 0, kt + 1); stB(nx, 0, kt + 1); stB(nx, 1, kt + 1); }
    S_BARRIER();
    mm16<0>(acc, af, bf);
    if (more) { VMCNT(3); } else { VMCNT(0); }
    S_BARRIER();
#pragma unroll
    for (int n = 0; n < 4; n++)
      bf[n] = __builtin_bit_cast(bf16x8, Bs[cur][(16 + wc * 4 + n) * 64 + lane]);
#pragma unroll
    for (int m = 0; m < 4; m++)
      af[m] = __builtin_bit_cast(bf16x8, As[cur][(8 + wr * 4 + m) * 64 + lane]);
    if (more) { stA(nx, 1, kt + 1); stB(nx, 2, kt + 1); stB(nx, 3, kt + 1); }
    S_BARRIER();
    mm16<0>(acc, af, bf);
    if (more) { VMCNT(3); }
    S_BARRIER();
    cur = nx;
  }

  epilogue<EPI>(acc, bias, res, outF, outB, N, bm0 + wr * 64, bn0 + wc * 64, g, li);
}

// ---------------------------------------------------------------------------
// V transpose: qkv V-section -> fragment-major V^T buffer (see R2 notes)
// ---------------------------------------------------------------------------
__global__ __launch_bounds__(256) void v_tr(const u16* __restrict__ qkv,
                                            u16* __restrict__ vfm) {
  __shared__ u16 Vl[64 * 72];
  const int t = threadIdx.x;
  const int bh = blockIdx.y;  // bb*16 + h
  const int bb = bh >> 4, h = bh & 15;
  const int kt = blockIdx.x;  // 0..31
#pragma unroll
  for (int bq = 0; bq < 2; bq++) {
    int c = t + bq * 256;  // 0..511
    int key = c >> 3, d0 = (c & 7) * 8;
    uint4 v = *(const uint4*)(qkv + (size_t)(bb * 2048 + kt * 64 + key) * 3072 + 2048 +
                              h * 64 + d0);
    *(uint4*)&Vl[key * 72 + d0] = v;
  }
  __syncthreads();
#pragma unroll
  for (int bq = 0; bq < 2; bq++) {
    int oc = t + bq * 256;
    int f = oc >> 6, l = oc & 63;
    int db = f >> 1, g32 = f & 1;
    int li = l & 15, g = l >> 4;
    u16 tmp[8];
#pragma unroll
    for (int e = 0; e < 8; e++) {
      int pk = g32 * 32 + ((e & 4) << 2) + g * 4 + (e & 3);
      tmp[e] = Vl[pk * 72 + db * 16 + li];
    }
    *(uint4*)(vfm + ((((size_t)bh * 32 + kt) * 8 + f) * 64 + l) * 8) = *(uint4*)tmp;
  }
}

// ---------------------------------------------------------------------------
// Flash attention, FIXED-BASE softmax, QBLK=128 x KVBLK=64 (R15 best config):
// each wave owns 32 q-rows (two row-groups), K/V staging + LDS reads
// amortized over 2x outputs. s_setprio now also wraps the QK cluster (T5).
// ---------------------------------------------------------------------------
__global__ __launch_bounds__(256) void attn_k(const u16* __restrict__ qkv,
                                              const u16* __restrict__ vfm,
                                              u16* __restrict__ ao) {
  __shared__ uint4 Ks[512];  // 8 frags x 64 x 16B (fragment-major K tile)
  __shared__ uint4 Vs[512];  // 8 frags x 64 x 16B (fragment-major V^T tile)
  const int t = threadIdx.x, lane = t & 63, wv = t >> 6;
  const int g = lane >> 4, li = lane & 15;
  const int bb = blockIdx.y >> 4, h = blockIdx.y & 15;
  const int q0 = blockIdx.x * 128 + wv * 32;

  const size_t qoff0 = (size_t)(bb * 2048 + q0 + li) * 3072 + h * 64 + g * 8;
  const size_t qoff1 = (size_t)(bb * 2048 + q0 + 16 + li) * 3072 + h * 64 + g * 8;
  bf16x8 qf00 = __builtin_bit_cast(bf16x8, *(const uint4*)(qkv + qoff0));
  bf16x8 qf01 = __builtin_bit_cast(bf16x8, *(const uint4*)(qkv + qoff0 + 32));
  bf16x8 qf10 = __builtin_bit_cast(bf16x8, *(const uint4*)(qkv + qoff1));
  bf16x8 qf11 = __builtin_bit_cast(bf16x8, *(const uint4*)(qkv + qoff1 + 32));

  const u16* kbase = qkv + (size_t)bb * 2048 * 3072 + 1024 + h * 64;
  const int f1 = wv + 4;
  const u16* ksrc0 = kbase + (size_t)(((wv >> 1) << 4) + li) * 3072 + ((wv & 1) << 5) + g * 8;
  const u16* ksrc1 = kbase + (size_t)(((f1 >> 1) << 4) + li) * 3072 + ((f1 & 1) << 5) + g * 8;
  const u16* vsrc0 = vfm + ((size_t)(bb * 16 + h) * 32) * 4096 + (wv * 64 + lane) * 8;
  const u16* vsrc1 = vsrc0 + 4 * 64 * 8;

  const f32x4 z4 = {0.f, 0.f, 0.f, 0.f};
  f32x4 Of0[4], Of1[4];
#pragma unroll
  for (int db = 0; db < 4; db++) { Of0[db] = z4; Of1[db] = z4; }
  f32x4 Ol0 = z4, Ol1 = z4;

  bf16x8 vone;
#pragma unroll
  for (int j = 0; j < 8; j++) vone[j] = (__bf16)1.0f;

  for (int tile = 0; tile < 32; tile++) {
    __syncthreads();  // previous tile's LDS reads done
    gload16(ksrc0 + (size_t)tile * 64 * 3072, (u16*)&Ks[wv * 64]);
    gload16(ksrc1 + (size_t)tile * 64 * 3072, (u16*)&Ks[(wv + 4) * 64]);
    gload16(vsrc0 + (size_t)tile * 4096, (u16*)&Vs[wv * 64]);
    gload16(vsrc1 + (size_t)tile * 4096, (u16*)&Vs[(wv + 4) * 64]);
    __syncthreads();  // vmcnt drained: tile ready

#pragma unroll
    for (int g32 = 0; g32 < 2; g32++) {
      uint4 pw0, pw1;
#pragma unroll
      for (int tt = 0; tt < 2; tt++) {
        int kb16 = g32 * 2 + tt;
        bf16x8 k0f = __builtin_bit_cast(bf16x8, Ks[(kb16 * 2 + 0) * 64 + lane]);
        bf16x8 k1f = __builtin_bit_cast(bf16x8, Ks[(kb16 * 2 + 1) * 64 + lane]);
        f32x4 s0 = z4, s1 = z4;
        __builtin_amdgcn_s_setprio(1);
        s0 = __builtin_amdgcn_mfma_f32_16x16x32_bf16(k0f, qf00, s0, 0, 0, 0);
        s0 = __builtin_amdgcn_mfma_f32_16x16x32_bf16(k1f, qf01, s0, 0, 0, 0);
        s1 = __builtin_amdgcn_mfma_f32_16x16x32_bf16(k0f, qf10, s1, 0, 0, 0);
        s1 = __builtin_amdgcn_mfma_f32_16x16x32_bf16(k1f, qf11, s1, 0, 0, 0);
        __builtin_amdgcn_s_setprio(0);
        float a0 = fexp2(s0[0]), a1 = fexp2(s0[1]), a2 = fexp2(s0[2]), a3 = fexp2(s0[3]);
        float b0 = fexp2(s1[0]), b1 = fexp2(s1[1]), b2 = fexp2(s1[2]), b3 = fexp2(s1[3]);
        u32 wa0, wa1, wb0, wb1;
        asm("v_cvt_pk_bf16_f32 %0, %1, %2" : "=v"(wa0) : "v"(a0), "v"(a1));
        asm("v_cvt_pk_bf16_f32 %0, %1, %2" : "=v"(wa1) : "v"(a2), "v"(a3));
        asm("v_cvt_pk_bf16_f32 %0, %1, %2" : "=v"(wb0) : "v"(b0), "v"(b1));
        asm("v_cvt_pk_bf16_f32 %0, %1, %2" : "=v"(wb1) : "v"(b2), "v"(b3));
        if (tt == 0) { pw0.x = wa0; pw0.y = wa1; pw1.x = wb0; pw1.y = wb1; }
        else         { pw0.z = wa0; pw0.w = wa1; pw1.z = wb0; pw1.w = wb1; }
      }
      bf16x8 pfa = __builtin_bit_cast(bf16x8, pw0);
      bf16x8 pfb = __builtin_bit_cast(bf16x8, pw1);
      __builtin_amdgcn_s_setprio(1);
#pragma unroll
      for (int db = 0; db < 4; db++) {
        bf16x8 vf = __builtin_bit_cast(bf16x8, Vs[(db * 2 + g32) * 64 + lane]);
        Of0[db] = __builtin_amdgcn_mfma_f32_16x16x32_bf16(pfa, vf, Of0[db], 0, 0, 0);
        Of1[db] = __builtin_amdgcn_mfma_f32_16x16x32_bf16(pfb, vf, Of1[db], 0, 0, 0);
      }
      Ol0 = __builtin_amdgcn_mfma_f32_16x16x32_bf16(pfa, vone, Ol0, 0, 0, 0);
      Ol1 = __builtin_amdgcn_mfma_f32_16x16x32_bf16(pfb, vone, Ol1, 0, 0, 0);
      __builtin_amdgcn_s_setprio(0);
    }
  }

  float inv0[4], inv1[4];
#pragma unroll
  for (int r = 0; r < 4; r++) { inv0[r] = 1.f / Ol0[r]; inv1[r] = 1.f / Ol1[r]; }
#pragma unroll
  for (int db = 0; db < 4; db++)
#pragma unroll
    for (int r = 0; r < 4; r++) {
      ao[(size_t)(bb * 2048 + q0 + 4 * g + r) * 1024 + h * 64 + db * 16 + li] =
          f2bf(Of0[db][r] * inv0[r]);
      ao[(size_t)(bb * 2048 + q0 + 16 + 4 * g + r) * 1024 + h * 64 + db * 16 + li] =
          f2bf(Of1[db][r] * inv1[r]);
    }
}

// ---------------------------------------------------------------------------
// Launcher
// ---------------------------------------------------------------------------
extern "C" void kernel_launch(void* const* d_in, const int* in_sizes, int n_in,
                              void* d_out, int out_size, void* d_ws, size_t ws_size,
                              hipStream_t stream) {
  const float* x = (const float*)d_in[0];
  const float* ln1g = (const float*)d_in[1];
  const float* ln1b = (const float*)d_in[2];
  const float* wqkv = (const float*)d_in[3];
  const float* bqkv = (const float*)d_in[4];
  const float* wout = (const float*)d_in[5];
  const float* bout = (const float*)d_in[6];
  const float* ln2g = (const float*)d_in[7];
  const float* ln2b = (const float*)d_in[8];
  const float* wff1 = (const float*)d_in[9];
  const float* bff1 = (const float*)d_in[10];
  const float* wff2 = (const float*)d_in[11];
  const float* bff2 = (const float*)d_in[12];
  float* outF = (float*)d_out;
  char* ws = (char*)d_ws;

  u16* wqkvT = (u16*)(ws + 0);         // 3072x1024 bf16 : 6291456 B (Q rows pre-scaled)
  u16* woutT = (u16*)(ws + 6291456);   // 1024x1024 bf16 : 2097152 B
  u16* wff1T = (u16*)(ws + 8388608);   // 4096x1024 bf16 : 8388608 B
  u16* wff2T = (u16*)(ws + 16777216);  // 1024x4096 bf16 : 8388608 B
  u16* hbuf  = (u16*)(ws + 25165824);  // 8192x1024 bf16 : 16777216 B
  u16* vfm   = (u16*)(ws + 25165824);  // 16777216 B; overlays hbuf (dead qkv->ln2)
  u16* qkvb  = (u16*)(ws + 41943040);  // 8192x3072 bf16 : 50331648 B
  u16* attnb = (u16*)(ws + 92274688);  // 8192x1024 bf16 : 16777216 B
  u16* ffn1b = qkvb;                   // 8192x4096 bf16 overlays qkv+attn (dead by then)
  float* biasq = (float*)attnb;        // 12KB scaled qkv bias; consumed by qkv GEMM
                                       // BEFORE attn_k overwrites attnb.

  transpose_cvt<<<dim3(96, 32), 256, 0, stream>>>(wqkv, wqkvT, 1024, 3072, QSCALE, 1024);
  transpose_cvt<<<dim3(32, 32), 256, 0, stream>>>(wout, woutT, 1024, 1024, 1.f, 0);
  transpose_cvt<<<dim3(128, 32), 256, 0, stream>>>(wff1, wff1T, 1024, 4096, 1.f, 0);
  transpose_cvt<<<dim3(32, 128), 256, 0, stream>>>(wff2, wff2T, 4096, 1024, 1.f, 0);
  prep_bias<<<12, 256, 0, stream>>>(bqkv, biasq);

  ln_k<<<8192, 256, 0, stream>>>(x, ln1g, ln1b, hbuf);
  // qkv: 8-wave 128x256 BK=64 (R15 config), grid 768 = 3 exact CU-waves
  gemm128<0><<<dim3(12, 64), 512, 0, stream>>>(hbuf, wqkvT, biasq, nullptr, nullptr, qkvb,
                                               8192, 3072, 1024);
  v_tr<<<dim3(32, 64), 256, 0, stream>>>(qkvb, vfm);
  // attn: QBLK=128 x KVBLK=64, grid 1024
  attn_k<<<dim3(16, 64), 256, 0, stream>>>(qkvb, vfm, attnb);
  gemm128<1><<<dim3(4, 64), 512, 0, stream>>>(attnb, woutT, bout, x, outF, nullptr,
                                              8192, 1024, 1024);
  ln_k<<<8192, 256, 0, stream>>>(outF, ln2g, ln2b, hbuf);
  // ffn1: 16-wave 256^2 kernel, grid 512 = exactly 2 CU-waves
  gemm256<2><<<dim3(16, 32), 1024, 0, stream>>>(hbuf, wff1T, bff1, nullptr, nullptr, ffn1b,
                                                8192, 4096, 1024);
  gemm128<1><<<dim3(4, 64), 512, 0, stream>>>(ffn1b, wff2T, bff2, outF, outF, nullptr,
                                              8192, 1024, 4096);

  (void)in_sizes;
  (void)n_in;
  (void)out_size;
  (void)ws_size;
}

// Round 19
// 427.601 us; speedup vs baseline: 1.1741x; 1.0058x over previous
//
#include <hip/hip_runtime.h>
#include <cstdint>
#include <cstddef>

typedef unsigned short u16;
typedef unsigned int   u32;
typedef __bf16 bf16x8 __attribute__((ext_vector_type(8)));
typedef float  f32x4  __attribute__((ext_vector_type(4)));
static_assert(sizeof(bf16x8) == 16, "bf16x8 must be 16B");
static_assert(sizeof(f32x4) == 16, "f32x4 must be 16B");

#define DEVI static __device__ __forceinline__

// 0.125 (1/sqrt(64)) * log2(e): folded into Q so QK^T lands in exp2-domain.
#define QSCALE 0.18033688011112042f

// bare v_exp_f32 (2^x): inputs here are range-bounded, so skip OCML's wrapper.
DEVI float fexp2(float x) {
  float r;
  asm("v_exp_f32 %0, %1" : "=v"(r) : "v"(x));
  return r;
}

// fp32 -> bf16, round-to-nearest-even
DEVI u16 f2bf(float x) {
  u32 u = __builtin_bit_cast(u32, x);
  u = (u + 0x7FFFu + ((u >> 16) & 1u)) >> 16;
  return (u16)u;
}

// direct HBM -> LDS, 16 bytes per lane. LDS dest must be wave-uniform base;
// HW writes base + lane*16. Global source is per-lane.
DEVI void gload16(const u16* g, u16* l) {
  __builtin_amdgcn_global_load_lds(
      (const __attribute__((address_space(1))) void*)g,
      (__attribute__((address_space(3))) void*)l, 16, 0, 0);
}

#define S_BARRIER() asm volatile("s_barrier" ::: "memory")
#define VMCNT(n) asm volatile("s_waitcnt vmcnt(" #n ")" ::: "memory")

// 16-MFMA cluster: acc[MO..MO+3][0..3] += af x bf   (MO compile-time)
template <int MO, int NACC>
DEVI void mm16(f32x4 (&acc)[NACC][4], const bf16x8 (&af)[4], const bf16x8 (&bf)[4]) {
  __builtin_amdgcn_s_setprio(1);
#pragma unroll
  for (int m = 0; m < 4; m++)
#pragma unroll
    for (int n = 0; n < 4; n++)
      acc[MO + m][n] =
          __builtin_amdgcn_mfma_f32_16x16x32_bf16(af[m], bf[n], acc[MO + m][n], 0, 0, 0);
  __builtin_amdgcn_s_setprio(0);
}

// ---------------------------------------------------------------------------
// Transpose + convert: W[K][N] fp32 -> WT[N][K] bf16; rows n < nscale get *scale
// ---------------------------------------------------------------------------
__global__ __launch_bounds__(256) void transpose_cvt(const float* __restrict__ W,
                                                     u16* __restrict__ WT,
                                                     int K, int N,
                                                     float scale, int nscale) {
  __shared__ float tile[32][33];
  int tx = threadIdx.x & 31, ty = threadIdx.x >> 5;  // 32 x 8
  int c0 = blockIdx.x * 32, r0 = blockIdx.y * 32;
#pragma unroll
  for (int i = 0; i < 4; i++)
    tile[ty + i * 8][tx] = W[(size_t)(r0 + ty + i * 8) * N + c0 + tx];
  __syncthreads();
#pragma unroll
  for (int i = 0; i < 4; i++) {
    int r = ty + i * 8;
    int n = c0 + r;
    float scl = (n < nscale) ? scale : 1.f;
    WT[(size_t)n * K + r0 + tx] = f2bf(tile[tx][r] * scl);
  }
}

// bias prep: biasq[i] = b[i] * (i < 1024 ? QSCALE : 1)   (3072 elems)
__global__ __launch_bounds__(256) void prep_bias(const float* __restrict__ b,
                                                 float* __restrict__ o) {
  int i = blockIdx.x * 256 + threadIdx.x;
  o[i] = b[i] * (i < 1024 ? QSCALE : 1.f);
}

// ---------------------------------------------------------------------------
// LayerNorm: X[row][1024] fp32 -> H[row][1024] bf16   (gamma, beta fp32).
// One WAVE per row (4 rows/block): pure shfl_xor reduction -- no LDS, no
// barriers (R18's cross-wave combine deleted). Each lane: 4x float4.
// ---------------------------------------------------------------------------
__global__ __launch_bounds__(256) void ln_k(const float* __restrict__ X,
                                            const float* __restrict__ gam,
                                            const float* __restrict__ bet,
                                            u16* __restrict__ H) {
  const int wv = threadIdx.x >> 6, lane = threadIdx.x & 63;
  const int row = blockIdx.x * 4 + wv;
  const float4* xr = (const float4*)(X + (size_t)row * 1024);
  float4 v[4];
  float s = 0.f, q = 0.f;
#pragma unroll
  for (int i = 0; i < 4; i++) {
    v[i] = xr[lane + i * 64];
    s += v[i].x + v[i].y + v[i].z + v[i].w;
    q += v[i].x * v[i].x + v[i].y * v[i].y + v[i].z * v[i].z + v[i].w * v[i].w;
  }
#pragma unroll
  for (int o = 32; o > 0; o >>= 1) {
    s += __shfl_xor(s, o);
    q += __shfl_xor(q, o);
  }
  const float mu = s * (1.f / 1024.f);
  const float rs = rsqrtf(q * (1.f / 1024.f) - mu * mu + 1e-5f);
#pragma unroll
  for (int i = 0; i < 4; i++) {
    float4 gv = ((const float4*)gam)[lane + i * 64];
    float4 bv = ((const float4*)bet)[lane + i * 64];
    ushort4 o;
    o.x = f2bf((v[i].x - mu) * rs * gv.x + bv.x);
    o.y = f2bf((v[i].y - mu) * rs * gv.y + bv.y);
    o.z = f2bf((v[i].z - mu) * rs * gv.z + bv.z);
    o.w = f2bf((v[i].w - mu) * rs * gv.w + bv.w);
    *(ushort4*)(H + (size_t)row * 1024 + (lane + i * 64) * 4) = o;
  }
}

// ---------------------------------------------------------------------------
// Shared epilogue: wave-tile write-out.
// EPI 2 gelu: sigmoid form (R13-verified, |delta| vs erf ~3e-3).
// ---------------------------------------------------------------------------
template <int EPI, int NACC>
DEVI void epilogue(f32x4 (&acc)[NACC][4], const float* bias, const float* res,
                   float* outF, u16* outB, int N, int rbase, int cbase, int g, int li) {
#pragma unroll
  for (int n = 0; n < 4; n++) {
    int c = cbase + n * 16 + li;
    float bv = bias[c];
#pragma unroll
    for (int a = 0; a < NACC; a++) {
      int rowb = rbase + a * 16 + g * 4;
#pragma unroll
      for (int r = 0; r < 4; r++) {
        size_t idx = (size_t)(rowb + r) * N + c;
        float v = acc[a][n][r] + bv;
        if constexpr (EPI == 1) {
          v += res[idx];
          outF[idx] = v;
        } else if constexpr (EPI == 2) {
          float te = fminf(v * (2.3020246f + 0.10294562f * v * v), 80.f);
          float e = fexp2(te);
          float rc;
          asm("v_rcp_f32 %0, %1" : "=v"(rc) : "v"(e + 1.f));
          v = v * e * rc;
          outB[idx] = f2bf(v);
        } else {
          outB[idx] = f2bf(v);
        }
      }
    }
  }
}

// ---------------------------------------------------------------------------
// gemm256: 256x256 tile, BK=64, 16 waves (1024 thr, 4Mx4N, per-wave 64x64).
// R10 winner -- unchanged. Double-buffered fragment-major LDS (128 KB),
// 2 phases/K-tile, 2 gloads/wave/phase, counted vmcnt(2) ledger.
// ---------------------------------------------------------------------------
template <int EPI>
__global__ __launch_bounds__(1024, 4) void gemm256(const u16* __restrict__ A,
                                                   const u16* __restrict__ Bt,
                                                   const float* __restrict__ bias,
                                                   const float* __restrict__ res,
                                                   float* __restrict__ outF,
                                                   u16* __restrict__ outB,
                                                   int M, int N, int K) {
  __shared__ uint4 As[2][2048];  // 32 frags (kh*16+fm) x 64 lanes, x2 buf
  __shared__ uint4 Bs[2][2048];
  const int t = threadIdx.x, lane = t & 63, wv = t >> 6;  // wv 0..15
  const int wr = wv >> 2, wc = wv & 3;                    // 4M x 4N wave grid
  const int li = lane & 15, g = lane >> 4;

  const int gx = gridDim.x;
  const int nwg = gx * gridDim.y;
  const int wg = blockIdx.y * gx + blockIdx.x;
  const int swz = (wg & 7) * (nwg >> 3) + (wg >> 3);
  const int bx = swz % gx, by = swz / gx;
  const int bm0 = by * 256, bn0 = bx * 256;

  f32x4 acc[4][4];
  const f32x4 z4 = {0.f, 0.f, 0.f, 0.f};
#pragma unroll
  for (int a = 0; a < 4; a++)
#pragma unroll
    for (int n = 0; n < 4; n++) acc[a][n] = z4;

  const u16* aB = A + (size_t)(bm0 + wv * 16 + li) * K + g * 8;
  const u16* bB = Bt + (size_t)(bn0 + wv * 16 + li) * K + g * 8;

  auto stA = [&](int buf, int kh, int kt) {
    gload16(aB + (size_t)kt * 64 + kh * 32, (u16*)&As[buf][(kh * 16 + wv) * 64]);
  };
  auto stB = [&](int buf, int kh, int kt) {
    gload16(bB + (size_t)kt * 64 + kh * 32, (u16*)&Bs[buf][(kh * 16 + wv) * 64]);
  };

  stA(0, 0, 0); stB(0, 0, 0);
  stA(0, 1, 0); stB(0, 1, 0);
  VMCNT(2);
  S_BARRIER();

  const int NT = K >> 6;
  int cur = 0;
  for (int kt = 0; kt < NT; kt++) {
    const int nx = cur ^ 1;
    const bool more = (kt + 1 < NT);
    bf16x8 af[4], bf[4];
    // ---- P0: kh0 ----
#pragma unroll
    for (int n = 0; n < 4; n++)
      bf[n] = __builtin_bit_cast(bf16x8, Bs[cur][(wc * 4 + n) * 64 + lane]);
#pragma unroll
    for (int m = 0; m < 4; m++)
      af[m] = __builtin_bit_cast(bf16x8, As[cur][(wr * 4 + m) * 64 + lane]);
    if (more) { stA(nx, 0, kt + 1); stB(nx, 0, kt + 1); }
    S_BARRIER();
    mm16<0>(acc, af, bf);
    if (more) { VMCNT(2); } else { VMCNT(0); }  // retire cur-kh1
    S_BARRIER();
    // ---- P1: kh1 ----
#pragma unroll
    for (int n = 0; n < 4; n++)
      bf[n] = __builtin_bit_cast(bf16x8, Bs[cur][(16 + wc * 4 + n) * 64 + lane]);
#pragma unroll
    for (int m = 0; m < 4; m++)
      af[m] = __builtin_bit_cast(bf16x8, As[cur][(16 + wr * 4 + m) * 64 + lane]);
    if (more) { stA(nx, 1, kt + 1); stB(nx, 1, kt + 1); }
    S_BARRIER();
    mm16<0>(acc, af, bf);
    if (more) { VMCNT(2); }  // retire nx-kh0 (for next P0)
    S_BARRIER();
    cur = nx;
  }

  epilogue<EPI>(acc, bias, res, outF, outB, N, bm0 + wr * 64, bn0 + wc * 64, g, li);
}

// ---------------------------------------------------------------------------
// gemm128: 128x256 tile, BK=64, 512 thr (8 waves 2Mx4N, per-wave 64x64).
// 2 phases/K-tile, 3 gloads/phase, vmcnt(3) at each phase tail.
// R15-proven version, LOCKED (BK=32 attempts falsified twice). 96KB LDS.
// ---------------------------------------------------------------------------
template <int EPI>
__global__ __launch_bounds__(512, 1) void gemm128(const u16* __restrict__ A,
                                                  const u16* __restrict__ Bt,
                                                  const float* __restrict__ bias,
                                                  const float* __restrict__ res,
                                                  float* __restrict__ outF,
                                                  u16* __restrict__ outB,
                                                  int M, int N, int K) {
  __shared__ uint4 As[2][1024];
  __shared__ uint4 Bs[2][2048];
  const int t = threadIdx.x, lane = t & 63, wv = t >> 6;
  const int wr = wv >> 2, wc = wv & 3;
  const int li = lane & 15, g = lane >> 4;

  const int gx = gridDim.x;
  const int nwg = gx * gridDim.y;
  const int wg = blockIdx.y * gx + blockIdx.x;
  const int swz = (wg & 7) * (nwg >> 3) + (wg >> 3);
  const int bx = swz % gx, by = swz / gx;
  const int bm0 = by * 128, bn0 = bx * 256;

  f32x4 acc[4][4];
  const f32x4 z4 = {0.f, 0.f, 0.f, 0.f};
#pragma unroll
  for (int a = 0; a < 4; a++)
#pragma unroll
    for (int n = 0; n < 4; n++) acc[a][n] = z4;

  const u16* aB = A + (size_t)(bm0 + wv * 16 + li) * K + g * 8;
  const u16* bB = Bt + (size_t)(bn0 + wv * 16 + li) * K + g * 8;
  const size_t rskip = (size_t)128 * K;

  auto stA = [&](int buf, int j, int kt) {
    gload16(aB + (size_t)kt * 64 + j * 32, (u16*)&As[buf][(j * 8 + wv) * 64]);
  };
  auto stB = [&](int buf, int j, int kt) {
    gload16(bB + (size_t)kt * 64 + ((j & 1) ? rskip : (size_t)0) + (j >> 1) * 32,
            (u16*)&Bs[buf][(j * 8 + wv) * 64]);
  };

  stA(0, 0, 0); stB(0, 0, 0); stB(0, 1, 0);
  stA(0, 1, 0); stB(0, 2, 0); stB(0, 3, 0);
  VMCNT(3);
  S_BARRIER();

  const int NT = K >> 6;
  int cur = 0;
  for (int kt = 0; kt < NT; kt++) {
    const int nx = cur ^ 1;
    const bool more = (kt + 1 < NT);
    bf16x8 af[4], bf[4];
#pragma unroll
    for (int n = 0; n < 4; n++)
      bf[n] = __builtin_bit_cast(bf16x8, Bs[cur][(wc * 4 + n) * 64 + lane]);
#pragma unroll
    for (int m = 0; m < 4; m++)
      af[m] = __builtin_bit_cast(bf16x8, As[cur][(wr * 4 + m) * 64 + lane]);
    if (more) { stA(nx, 0, kt + 1); stB(nx, 0, kt + 1); stB(nx, 1, kt + 1); }
    S_BARRIER();
    mm16<0>(acc, af, bf);
    if (more) { VMCNT(3); } else { VMCNT(0); }
    S_BARRIER();
#pragma unroll
    for (int n = 0; n < 4; n++)
      bf[n] = __builtin_bit_cast(bf16x8, Bs[cur][(16 + wc * 4 + n) * 64 + lane]);
#pragma unroll
    for (int m = 0; m < 4; m++)
      af[m] = __builtin_bit_cast(bf16x8, As[cur][(8 + wr * 4 + m) * 64 + lane]);
    if (more) { stA(nx, 1, kt + 1); stB(nx, 2, kt + 1); stB(nx, 3, kt + 1); }
    S_BARRIER();
    mm16<0>(acc, af, bf);
    if (more) { VMCNT(3); }
    S_BARRIER();
    cur = nx;
  }

  epilogue<EPI>(acc, bias, res, outF, outB, N, bm0 + wr * 64, bn0 + wc * 64, g, li);
}

// ---------------------------------------------------------------------------
// V transpose: qkv V-section -> fragment-major V^T buffer (see R2 notes)
// ---------------------------------------------------------------------------
__global__ __launch_bounds__(256) void v_tr(const u16* __restrict__ qkv,
                                            u16* __restrict__ vfm) {
  __shared__ u16 Vl[64 * 72];
  const int t = threadIdx.x;
  const int bh = blockIdx.y;  // bb*16 + h
  const int bb = bh >> 4, h = bh & 15;
  const int kt = blockIdx.x;  // 0..31
#pragma unroll
  for (int bq = 0; bq < 2; bq++) {
    int c = t + bq * 256;  // 0..511
    int key = c >> 3, d0 = (c & 7) * 8;
    uint4 v = *(const uint4*)(qkv + (size_t)(bb * 2048 + kt * 64 + key) * 3072 + 2048 +
                              h * 64 + d0);
    *(uint4*)&Vl[key * 72 + d0] = v;
  }
  __syncthreads();
#pragma unroll
  for (int bq = 0; bq < 2; bq++) {
    int oc = t + bq * 256;
    int f = oc >> 6, l = oc & 63;
    int db = f >> 1, g32 = f & 1;
    int li = l & 15, g = l >> 4;
    u16 tmp[8];
#pragma unroll
    for (int e = 0; e < 8; e++) {
      int pk = g32 * 32 + ((e & 4) << 2) + g * 4 + (e & 3);
      tmp[e] = Vl[pk * 72 + db * 16 + li];
    }
    *(uint4*)(vfm + ((((size_t)bh * 32 + kt) * 8 + f) * 64 + l) * 8) = *(uint4*)tmp;
  }
}

// ---------------------------------------------------------------------------
// Flash attention, FIXED-BASE softmax, QBLK=128 x KVBLK=64 (R15/R18 config).
// ---------------------------------------------------------------------------
__global__ __launch_bounds__(256) void attn_k(const u16* __restrict__ qkv,
                                              const u16* __restrict__ vfm,
                                              u16* __restrict__ ao) {
  __shared__ uint4 Ks[512];  // 8 frags x 64 x 16B (fragment-major K tile)
  __shared__ uint4 Vs[512];  // 8 frags x 64 x 16B (fragment-major V^T tile)
  const int t = threadIdx.x, lane = t & 63, wv = t >> 6;
  const int g = lane >> 4, li = lane & 15;
  const int bb = blockIdx.y >> 4, h = blockIdx.y & 15;
  const int q0 = blockIdx.x * 128 + wv * 32;

  const size_t qoff0 = (size_t)(bb * 2048 + q0 + li) * 3072 + h * 64 + g * 8;
  const size_t qoff1 = (size_t)(bb * 2048 + q0 + 16 + li) * 3072 + h * 64 + g * 8;
  bf16x8 qf00 = __builtin_bit_cast(bf16x8, *(const uint4*)(qkv + qoff0));
  bf16x8 qf01 = __builtin_bit_cast(bf16x8, *(const uint4*)(qkv + qoff0 + 32));
  bf16x8 qf10 = __builtin_bit_cast(bf16x8, *(const uint4*)(qkv + qoff1));
  bf16x8 qf11 = __builtin_bit_cast(bf16x8, *(const uint4*)(qkv + qoff1 + 32));

  const u16* kbase = qkv + (size_t)bb * 2048 * 3072 + 1024 + h * 64;
  const int f1 = wv + 4;
  const u16* ksrc0 = kbase + (size_t)(((wv >> 1) << 4) + li) * 3072 + ((wv & 1) << 5) + g * 8;
  const u16* ksrc1 = kbase + (size_t)(((f1 >> 1) << 4) + li) * 3072 + ((f1 & 1) << 5) + g * 8;
  const u16* vsrc0 = vfm + ((size_t)(bb * 16 + h) * 32) * 4096 + (wv * 64 + lane) * 8;
  const u16* vsrc1 = vsrc0 + 4 * 64 * 8;

  const f32x4 z4 = {0.f, 0.f, 0.f, 0.f};
  f32x4 Of0[4], Of1[4];
#pragma unroll
  for (int db = 0; db < 4; db++) { Of0[db] = z4; Of1[db] = z4; }
  f32x4 Ol0 = z4, Ol1 = z4;

  bf16x8 vone;
#pragma unroll
  for (int j = 0; j < 8; j++) vone[j] = (__bf16)1.0f;

  for (int tile = 0; tile < 32; tile++) {
    __syncthreads();  // previous tile's LDS reads done
    gload16(ksrc0 + (size_t)tile * 64 * 3072, (u16*)&Ks[wv * 64]);
    gload16(ksrc1 + (size_t)tile * 64 * 3072, (u16*)&Ks[(wv + 4) * 64]);
    gload16(vsrc0 + (size_t)tile * 4096, (u16*)&Vs[wv * 64]);
    gload16(vsrc1 + (size_t)tile * 4096, (u16*)&Vs[(wv + 4) * 64]);
    __syncthreads();  // vmcnt drained: tile ready

#pragma unroll
    for (int g32 = 0; g32 < 2; g32++) {
      uint4 pw0, pw1;
#pragma unroll
      for (int tt = 0; tt < 2; tt++) {
        int kb16 = g32 * 2 + tt;
        bf16x8 k0f = __builtin_bit_cast(bf16x8, Ks[(kb16 * 2 + 0) * 64 + lane]);
        bf16x8 k1f = __builtin_bit_cast(bf16x8, Ks[(kb16 * 2 + 1) * 64 + lane]);
        f32x4 s0 = z4, s1 = z4;
        __builtin_amdgcn_s_setprio(1);
        s0 = __builtin_amdgcn_mfma_f32_16x16x32_bf16(k0f, qf00, s0, 0, 0, 0);
        s0 = __builtin_amdgcn_mfma_f32_16x16x32_bf16(k1f, qf01, s0, 0, 0, 0);
        s1 = __builtin_amdgcn_mfma_f32_16x16x32_bf16(k0f, qf10, s1, 0, 0, 0);
        s1 = __builtin_amdgcn_mfma_f32_16x16x32_bf16(k1f, qf11, s1, 0, 0, 0);
        __builtin_amdgcn_s_setprio(0);
        float a0 = fexp2(s0[0]), a1 = fexp2(s0[1]), a2 = fexp2(s0[2]), a3 = fexp2(s0[3]);
        float b0 = fexp2(s1[0]), b1 = fexp2(s1[1]), b2 = fexp2(s1[2]), b3 = fexp2(s1[3]);
        u32 wa0, wa1, wb0, wb1;
        asm("v_cvt_pk_bf16_f32 %0, %1, %2" : "=v"(wa0) : "v"(a0), "v"(a1));
        asm("v_cvt_pk_bf16_f32 %0, %1, %2" : "=v"(wa1) : "v"(a2), "v"(a3));
        asm("v_cvt_pk_bf16_f32 %0, %1, %2" : "=v"(wb0) : "v"(b0), "v"(b1));
        asm("v_cvt_pk_bf16_f32 %0, %1, %2" : "=v"(wb1) : "v"(b2), "v"(b3));
        if (tt == 0) { pw0.x = wa0; pw0.y = wa1; pw1.x = wb0; pw1.y = wb1; }
        else         { pw0.z = wa0; pw0.w = wa1; pw1.z = wb0; pw1.w = wb1; }
      }
      bf16x8 pfa = __builtin_bit_cast(bf16x8, pw0);
      bf16x8 pfb = __builtin_bit_cast(bf16x8, pw1);
      __builtin_amdgcn_s_setprio(1);
#pragma unroll
      for (int db = 0; db < 4; db++) {
        bf16x8 vf = __builtin_bit_cast(bf16x8, Vs[(db * 2 + g32) * 64 + lane]);
        Of0[db] = __builtin_amdgcn_mfma_f32_16x16x32_bf16(pfa, vf, Of0[db], 0, 0, 0);
        Of1[db] = __builtin_amdgcn_mfma_f32_16x16x32_bf16(pfb, vf, Of1[db], 0, 0, 0);
      }
      Ol0 = __builtin_amdgcn_mfma_f32_16x16x32_bf16(pfa, vone, Ol0, 0, 0, 0);
      Ol1 = __builtin_amdgcn_mfma_f32_16x16x32_bf16(pfb, vone, Ol1, 0, 0, 0);
      __builtin_amdgcn_s_setprio(0);
    }
  }

  float inv0[4], inv1[4];
#pragma unroll
  for (int r = 0; r < 4; r++) { inv0[r] = 1.f / Ol0[r]; inv1[r] = 1.f / Ol1[r]; }
#pragma unroll
  for (int db = 0; db < 4; db++)
#pragma unroll
    for (int r = 0; r < 4; r++) {
      ao[(size_t)(bb * 2048 + q0 + 4 * g + r) * 1024 + h * 64 + db * 16 + li] =
          f2bf(Of0[db][r] * inv0[r]);
      ao[(size_t)(bb * 2048 + q0 + 16 + 4 * g + r) * 1024 + h * 64 + db * 16 + li] =
          f2bf(Of1[db][r] * inv1[r]);
    }
}

// ---------------------------------------------------------------------------
// Launcher
// ---------------------------------------------------------------------------
extern "C" void kernel_launch(void* const* d_in, const int* in_sizes, int n_in,
                              void* d_out, int out_size, void* d_ws, size_t ws_size,
                              hipStream_t stream) {
  const float* x = (const float*)d_in[0];
  const float* ln1g = (const float*)d_in[1];
  const float* ln1b = (const float*)d_in[2];
  const float* wqkv = (const float*)d_in[3];
  const float* bqkv = (const float*)d_in[4];
  const float* wout = (const float*)d_in[5];
  const float* bout = (const float*)d_in[6];
  const float* ln2g = (const float*)d_in[7];
  const float* ln2b = (const float*)d_in[8];
  const float* wff1 = (const float*)d_in[9];
  const float* bff1 = (const float*)d_in[10];
  const float* wff2 = (const float*)d_in[11];
  const float* bff2 = (const float*)d_in[12];
  float* outF = (float*)d_out;
  char* ws = (char*)d_ws;

  u16* wqkvT = (u16*)(ws + 0);         // 3072x1024 bf16 : 6291456 B (Q rows pre-scaled)
  u16* woutT = (u16*)(ws + 6291456);   // 1024x1024 bf16 : 2097152 B
  u16* wff1T = (u16*)(ws + 8388608);   // 4096x1024 bf16 : 8388608 B
  u16* wff2T = (u16*)(ws + 16777216);  // 1024x4096 bf16 : 8388608 B
  u16* hbuf  = (u16*)(ws + 25165824);  // 8192x1024 bf16 : 16777216 B
  u16* vfm   = (u16*)(ws + 25165824);  // 16777216 B; overlays hbuf (dead qkv->ln2)
  u16* qkvb  = (u16*)(ws + 41943040);  // 8192x3072 bf16 : 50331648 B
  u16* attnb = (u16*)(ws + 92274688);  // 8192x1024 bf16 : 16777216 B
  u16* ffn1b = qkvb;                   // 8192x4096 bf16 overlays qkv+attn (dead by then)
  float* biasq = (float*)attnb;        // 12KB scaled qkv bias; consumed by qkv GEMM
                                       // BEFORE attn_k overwrites attnb.

  transpose_cvt<<<dim3(96, 32), 256, 0, stream>>>(wqkv, wqkvT, 1024, 3072, QSCALE, 1024);
  transpose_cvt<<<dim3(32, 32), 256, 0, stream>>>(wout, woutT, 1024, 1024, 1.f, 0);
  transpose_cvt<<<dim3(128, 32), 256, 0, stream>>>(wff1, wff1T, 1024, 4096, 1.f, 0);
  transpose_cvt<<<dim3(32, 128), 256, 0, stream>>>(wff2, wff2T, 4096, 1024, 1.f, 0);
  prep_bias<<<12, 256, 0, stream>>>(bqkv, biasq);

  ln_k<<<2048, 256, 0, stream>>>(x, ln1g, ln1b, hbuf);
  // qkv: 8-wave 128x256 BK=64 (R15 config), grid 768 = 3 exact CU-waves
  gemm128<0><<<dim3(12, 64), 512, 0, stream>>>(hbuf, wqkvT, biasq, nullptr, nullptr, qkvb,
                                               8192, 3072, 1024);
  v_tr<<<dim3(32, 64), 256, 0, stream>>>(qkvb, vfm);
  // attn: QBLK=128 x KVBLK=64, grid 1024
  attn_k<<<dim3(16, 64), 256, 0, stream>>>(qkvb, vfm, attnb);
  gemm128<1><<<dim3(4, 64), 512, 0, stream>>>(attnb, woutT, bout, x, outF, nullptr,
                                              8192, 1024, 1024);
  ln_k<<<2048, 256, 0, stream>>>(outF, ln2g, ln2b, hbuf);
  // ffn1: 16-wave 256^2 kernel, grid 512 = exactly 2 CU-waves
  gemm256<2><<<dim3(16, 32), 1024, 0, stream>>>(hbuf, wff1T, bff1, nullptr, nullptr, ffn1b,
                                                8192, 4096, 1024);
  gemm128<1><<<dim3(4, 64), 512, 0, stream>>>(ffn1b, wff2T, bff2, outF, outF, nullptr,
                                              8192, 1024, 4096);

  (void)in_sizes;
  (void)n_in;
  (void)out_size;
  (void)ws_size;
}